// Round 4
// baseline (1273.843 us; speedup 1.0000x reference)
//
#include <hip/hip_runtime.h>
#include <math.h>

#define CC 192
#define TTT 768
#define PP 29
#define LOG2PI_F 1.8378770664093453f
#define WSLOT 36864   // 192*192
#define PSLOT 5568    // 29*192
#define XSTR 200      // ushort stride for [t][c] bf16 tiles

typedef __attribute__((ext_vector_type(8))) short short8;
typedef __attribute__((ext_vector_type(4))) float floatx4;
union Frag { int4 i; short8 s; };

__device__ __forceinline__ float geluf(float x){
  float u = 1.5957691216057308f * (x + 0.044715f*x*x*x);
  return x * __builtin_amdgcn_rcpf(1.f + __expf(-u));
}
__device__ __forceinline__ float softplus_f(float x){
  return (x > 20.f) ? x : log1pf(__expf(x));
}
__device__ __forceinline__ float logsig_f(float x){
  return -softplus_f(-x);
}
__device__ __forceinline__ unsigned short f2bf(float f){
  unsigned int u = __builtin_bit_cast(unsigned int, f);
  u += 0x7fffu + ((u >> 16) & 1u);
  return (unsigned short)(u >> 16);
}
__device__ __forceinline__ unsigned int packbf2(float a0, float a1){
  return (unsigned int)f2bf(a0) | ((unsigned int)f2bf(a1) << 16);
}
__device__ __forceinline__ void unbf2(unsigned int u, float& lo, float& hi){
  lo = __builtin_bit_cast(float, u << 16);
  hi = __builtin_bit_cast(float, u & 0xffff0000u);
}
__device__ __forceinline__ void f4arr(float4 v, float* o){ o[0]=v.x;o[1]=v.y;o[2]=v.z;o[3]=v.w; }

// ---------------- weight f32 -> bf16 conversion (33 conv slots + 8 proj slots) ----------------
__global__ __launch_bounds__(256) void convert_w_k(
    const float* __restrict__ p0, const float* __restrict__ p1,
    const float* __restrict__ p2, const float* __restrict__ p3,
    const float* __restrict__ p4, const float* __restrict__ p5,
    const float* __restrict__ p6, const float* __restrict__ p7,
    const float* __restrict__ p8, unsigned short* __restrict__ Wb){
  int i = blockIdx.x*256 + threadIdx.x;
  const int totalA = 33*WSLOT;
  const int total = totalA + 8*PSLOT;
  if (i >= total) return;
  const float* src;
  if (i < totalA){
    int slot = i / WSLOT, r = i % WSLOT;
    if      (slot == 0) src = p0 + r;
    else if (slot == 1) src = p1 + r;
    else if (slot == 2) src = p2 + r;
    else if (slot < 6)  src = p3 + (size_t)(slot-3)*WSLOT + r;
    else if (slot < 9)  src = p4 + (size_t)(slot-6)*WSLOT + r;
    else if (slot < 21) src = p5 + (size_t)(slot-9)*WSLOT + r;
    else                src = p6 + (size_t)(slot-21)*WSLOT + r;
  } else {
    int r2 = i - totalA;
    int ps = r2 / PSLOT, rr = r2 % PSLOT;
    src = (ps < 4) ? (p7 + (size_t)ps*PSLOT + rr) : (p8 + (size_t)(ps-4)*PSLOT + rr);
  }
  Wb[i] = f2bf(*src);
}

// ---------------- conv 192x192 (bf16 MFMA), staged input ----------------
__global__ __launch_bounds__(256) void conv_cc_k(
    const float* __restrict__ in, const unsigned short* __restrict__ Wb,
    const float* __restrict__ bias, const float* __restrict__ mask,
    const float* __restrict__ addsrc, float* __restrict__ out, int mode){
  __shared__ unsigned short bufX[32*XSTR];
  int b = blockIdx.y, t0 = blockIdx.x*32;
  int tid = threadIdx.x;
  const float* inb = in + (size_t)b*CC*TTT;
  for (int task=tid; task<384; task+=256){
    int qq = task % 48, ck = task / 48;          // rows qq*4.., t-chunk ck*4..
    int gt = t0 + ck*4;
    const float* r0 = inb + (size_t)(qq*4)*TTT + gt;
    float e0[4],e1[4],e2[4],e3[4];
    f4arr(*(const float4*)r0, e0);
    f4arr(*(const float4*)(r0 + TTT), e1);
    f4arr(*(const float4*)(r0 + 2*TTT), e2);
    f4arr(*(const float4*)(r0 + 3*TTT), e3);
    #pragma unroll
    for (int e=0;e<4;e++){
      uint2 wv; wv.x = packbf2(e0[e], e1[e]); wv.y = packbf2(e2[e], e3[e]);
      *(uint2*)&bufX[(ck*4+e)*XSTR + qq*4] = wv;
    }
  }
  __syncthreads();
  int w = tid >> 6, lane = tid & 63;
  int n16 = lane & 15, quad = lane >> 4;
  Frag af[3][6];
  #pragma unroll
  for (int ct=0; ct<3; ct++){
    int co = w*48 + ct*16 + n16;
    #pragma unroll
    for (int k=0;k<6;k++)
      af[ct][k].i = *(const int4*)(Wb + (size_t)co*CC + k*32 + quad*8);
  }
  floatx4 acc[3][2];
  #pragma unroll
  for (int ct=0;ct<3;ct++)
    #pragma unroll
    for (int tt=0;tt<2;tt++)
      acc[ct][tt] = (floatx4){0.f,0.f,0.f,0.f};
  #pragma unroll
  for (int k=0;k<6;k++){
    Frag bf[2];
    #pragma unroll
    for (int tt=0;tt<2;tt++)
      bf[tt].i = *(const int4*)&bufX[(tt*16+n16)*XSTR + k*32 + quad*8];
    #pragma unroll
    for (int ct=0;ct<3;ct++)
      #pragma unroll
      for (int tt=0;tt<2;tt++)
        acc[ct][tt] = __builtin_amdgcn_mfma_f32_16x16x32_bf16(af[ct][k].s, bf[tt].s, acc[ct][tt], 0,0,0);
  }
  #pragma unroll
  for (int ct=0;ct<3;ct++){
    int cobase = w*48 + ct*16 + quad*4;
    float4 b4 = *(const float4*)(bias + cobase);
    float ba[4] = {b4.x, b4.y, b4.z, b4.w};
    #pragma unroll
    for (int tt=0;tt<2;tt++){
      int t = t0 + tt*16 + n16;
      float mv = (mode >= 1) ? mask[(size_t)b*TTT + t] : 1.f;
      #pragma unroll
      for (int r=0;r<4;r++){
        float v = acc[ct][tt][r] + ba[r];
        if (mode >= 1) v *= mv;
        if (mode == 2) v += addsrc[((size_t)b*CC + cobase + r)*TTT + t];
        out[((size_t)b*CC + cobase + r)*TTT + t] = v;
      }
    }
  }
}

// ---------------- fused DDS layer, staged halo tile ----------------
// srcmode 0: x from `in`; srcmode 1: x[c][t] = pw1[c]*src1[t]+pb1[c] (+ g[c][t])
// outmode 0: residual output to `out`; outmode 1: proj + RQS spline
__global__ __launch_bounds__(256) void dds_fused_k(
    const float* __restrict__ in,
    const float* __restrict__ src1, int s1s,
    const float* __restrict__ pw1, const float* __restrict__ pb1,
    const float* __restrict__ g,
    float* __restrict__ out,
    const float* __restrict__ mask,
    const float* __restrict__ dw, const float* __restrict__ db,
    const float* __restrict__ g0, const float* __restrict__ b0,
    const unsigned short* __restrict__ Wb, const float* __restrict__ pb,
    const float* __restrict__ g1, const float* __restrict__ b1,
    int dil, int srcmode, int outmode,
    const unsigned short* __restrict__ projWb, const float* __restrict__ projB,
    float* __restrict__ z, int zs, float* __restrict__ acco){
  __shared__ unsigned short X[64*XSTR];      // bf16 [window t][c] halo tile
  __shared__ unsigned short bufX[32*XSTR];   // bf16 [t][c] activations
  __shared__ float par[2112];                // dw(576) db g0 b0 g1 b1 pw1 pb1 pb
  __shared__ float redS[32*17], redQ[32*17];
  __shared__ float mst[32], rst[32];
  __shared__ float zwin[64];
  float* pro = (float*)X;                    // alias; used only after X is dead

  int b = blockIdx.y, t0 = blockIdx.x*32;
  int tid = threadIdx.x;
  int tl = tid & 31, cs = tid >> 5;
  int c0 = cs*24;
  int tg = t0 + tl;
  int ws0 = t0 - 16;

  // stage per-channel params
  for (int i=tid; i<576; i+=256) par[i] = dw[i];
  if (tid < 192){
    par[576+tid]  = db[tid];
    par[768+tid]  = g0[tid];
    par[960+tid]  = b0[tid];
    par[1152+tid] = g1[tid];
    par[1344+tid] = b1[tid];
    par[1920+tid] = pb[tid];
    if (srcmode == 1){ par[1536+tid] = pw1[tid]; par[1728+tid] = pb1[tid]; }
  }
  // stage X tile (coalesced float4 -> bf16 transpose)
  const float* stg = (srcmode == 0) ? (in + (size_t)b*CC*TTT)
                                    : (g ? g + (size_t)b*CC*TTT : nullptr);
  if (stg){
    #pragma unroll
    for (int p=0;p<3;p++){
      int task = p*256 + tid;                  // 768 tasks: 48 row-quads x 16 t-chunks
      int qq = task % 48, ck = task / 48;
      int gt = ws0 + ck*4;
      gt = gt < 0 ? 0 : (gt > TTT-4 ? TTT-4 : gt);   // halo slots out of range are never read
      const float* r0 = stg + (size_t)(qq*4)*TTT + gt;
      float e0[4],e1[4],e2[4],e3[4];
      f4arr(*(const float4*)r0, e0);
      f4arr(*(const float4*)(r0 + TTT), e1);
      f4arr(*(const float4*)(r0 + 2*TTT), e2);
      f4arr(*(const float4*)(r0 + 3*TTT), e3);
      #pragma unroll
      for (int e=0;e<4;e++){
        uint2 wv; wv.x = packbf2(e0[e], e1[e]); wv.y = packbf2(e2[e], e3[e]);
        *(uint2*)&X[(ck*4+e)*XSTR + qq*4] = wv;
      }
    }
  }
  if (srcmode == 1 && tid < 64){
    int gt = ws0 + tid; gt = gt < 0 ? 0 : (gt > TTT-1 ? TTT-1 : gt);
    zwin[tid] = src1[(size_t)b*s1s + gt];
  }
  const float* mk = mask + (size_t)b*TTT;
  int tlo = tg - dil, thi = tg + dil;
  int tloC = tlo < 0 ? 0 : tlo, thiC = thi >= TTT ? TTT-1 : thi;
  float mc  = mk[tg];
  float mlv = mk[tloC] * (tlo >= 0 ? 1.f : 0.f);
  float mrv = mk[thiC] * (thi < TTT ? 1.f : 0.f);
  __syncthreads();

  // P1: depthwise from LDS
  int idxL = 16 + tl - dil, idxC = 16 + tl, idxR = 16 + tl + dil;
  float zl=0.f, zc=0.f, zr=0.f;
  if (srcmode == 1){ zl = zwin[idxL]; zc = zwin[idxC]; zr = zwin[idxR]; }
  float v[24];
  float s = 0.f, q = 0.f;
  #pragma unroll
  for (int j=0;j<6;j++){
    int c = c0 + j*4;
    float xl[4]={0,0,0,0}, xc4[4]={0,0,0,0}, xr4[4]={0,0,0,0};
    if (stg){
      uint2 ul = *(uint2*)&X[idxL*XSTR + c];
      uint2 uc = *(uint2*)&X[idxC*XSTR + c];
      uint2 ur = *(uint2*)&X[idxR*XSTR + c];
      unbf2(ul.x, xl[0], xl[1]);  unbf2(ul.y, xl[2], xl[3]);
      unbf2(uc.x, xc4[0], xc4[1]); unbf2(uc.y, xc4[2], xc4[3]);
      unbf2(ur.x, xr4[0], xr4[1]); unbf2(ur.y, xr4[2], xr4[3]);
    }
    #pragma unroll
    for (int e=0;e<4;e++){
      int cc = c + e;
      if (srcmode == 1){
        float pwc = par[1536+cc], pbc = par[1728+cc];
        xl[e]  += fmaf(pwc, zl, pbc);
        xc4[e] += fmaf(pwc, zc, pbc);
        xr4[e] += fmaf(pwc, zr, pbc);
      }
      float val = fmaf(par[cc*3], xl[e]*mlv, fmaf(par[cc*3+1], xc4[e]*mc,
                  fmaf(par[cc*3+2], xr4[e]*mrv, par[576+cc])));
      v[j*4+e] = val; s += val; q = fmaf(val, val, q);
    }
  }
  redS[tl*17+cs] = s; redQ[tl*17+cs] = q;
  __syncthreads();
  if (tid < 32){
    float S=0.f, Q=0.f;
    #pragma unroll
    for (int j=0;j<8;j++){ S += redS[tid*17+j]; Q += redQ[tid*17+j]; }
    float m = S*(1.f/CC);
    mst[tid] = m; rst[tid] = rsqrtf(Q*(1.f/CC) - m*m + 1e-5f);
  }
  __syncthreads();
  // P3: LN + gelu -> bf16
  {
    float mm = mst[tl], rr = rst[tl];
    #pragma unroll
    for (int j=0;j<12;j++){
      int c = c0 + 2*j;
      float a0 = geluf((v[2*j]  -mm)*rr*par[768+c]   + par[960+c]);
      float a1 = geluf((v[2*j+1]-mm)*rr*par[768+c+1] + par[960+c+1]);
      *(unsigned int*)&bufX[tl*XSTR + c] = packbf2(a0, a1);
    }
  }
  __syncthreads();
  // P4: conv via MFMA, stats from registers
  int w = tid >> 6, lane = tid & 63;
  int n16 = lane & 15, quad = lane >> 4;
  floatx4 acc[3][2];
  {
    Frag af[3][6];
    #pragma unroll
    for (int ct=0; ct<3; ct++){
      int co = w*48 + ct*16 + n16;
      #pragma unroll
      for (int k=0;k<6;k++)
        af[ct][k].i = *(const int4*)(Wb + (size_t)co*CC + k*32 + quad*8);
    }
    #pragma unroll
    for (int ct=0;ct<3;ct++)
      #pragma unroll
      for (int tt=0;tt<2;tt++)
        acc[ct][tt] = (floatx4){0.f,0.f,0.f,0.f};
    #pragma unroll
    for (int k=0;k<6;k++){
      Frag bf[2];
      #pragma unroll
      for (int tt=0;tt<2;tt++)
        bf[tt].i = *(const int4*)&bufX[(tt*16+n16)*XSTR + k*32 + quad*8];
      #pragma unroll
      for (int ct=0;ct<3;ct++)
        #pragma unroll
        for (int tt=0;tt<2;tt++)
          acc[ct][tt] = __builtin_amdgcn_mfma_f32_16x16x32_bf16(af[ct][k].s, bf[tt].s, acc[ct][tt], 0,0,0);
    }
  }
  // bias + per-t partial stats
  #pragma unroll
  for (int ct=0;ct<3;ct++){
    int cobase = w*48 + ct*16 + quad*4;
    #pragma unroll
    for (int tt=0;tt<2;tt++)
      #pragma unroll
      for (int r=0;r<4;r++)
        acc[ct][tt][r] += par[1920+cobase+r];
  }
  #pragma unroll
  for (int tt=0;tt<2;tt++){
    float ps=0.f, pq=0.f;
    #pragma unroll
    for (int ct=0;ct<3;ct++)
      #pragma unroll
      for (int r=0;r<4;r++){ float vv = acc[ct][tt][r]; ps += vv; pq = fmaf(vv,vv,pq); }
    int t = tt*16 + n16;
    redS[t*17 + (w*4+quad)] = ps;
    redQ[t*17 + (w*4+quad)] = pq;
  }
  __syncthreads();
  if (tid < 32){
    float S=0.f, Q=0.f;
    #pragma unroll
    for (int j=0;j<16;j++){ S += redS[tid*17+j]; Q += redQ[tid*17+j]; }
    float m = S*(1.f/CC);
    mst[tid] = m; rst[tid] = rsqrtf(Q*(1.f/CC) - m*m + 1e-5f);
  }
  __syncthreads();
  // P6: LN + gelu + residual (from registers + X)
  #pragma unroll
  for (int ct=0;ct<3;ct++){
    int cobase = w*48 + ct*16 + quad*4;
    #pragma unroll
    for (int tt=0;tt<2;tt++){
      int t = tt*16 + n16;
      float mm = mst[t], rr = rst[t];
      float xcv[4] = {0,0,0,0};
      if (stg){
        uint2 ux = *(uint2*)&X[(16+t)*XSTR + cobase];
        unbf2(ux.x, xcv[0], xcv[1]); unbf2(ux.y, xcv[2], xcv[3]);
      }
      if (srcmode == 1){
        float zcv = zwin[16+t];
        #pragma unroll
        for (int r=0;r<4;r++)
          xcv[r] += fmaf(par[1536+cobase+r], zcv, par[1728+cobase+r]);
      }
      float hh[4];
      #pragma unroll
      for (int r=0;r<4;r++){
        float val = (acc[ct][tt][r] - mm)*rr*par[1152+cobase+r] + par[1344+cobase+r];
        hh[r] = xcv[r] + geluf(val);
      }
      if (outmode == 0){
        #pragma unroll
        for (int r=0;r<4;r++)
          out[((size_t)b*CC + cobase + r)*TTT + t0 + t] = hh[r];
      } else {
        uint2 wv; wv.x = packbf2(hh[0], hh[1]); wv.y = packbf2(hh[2], hh[3]);
        *(uint2*)&bufX[t*XSTR + cobase] = wv;
      }
    }
  }
  if (outmode == 0) return;
  __syncthreads();   // bufX (h, bf16) complete; X dead -> pro alias OK
  // proj: wave 0 computes 29x192 @ 192x32
  if (w == 0){
    Frag af2[2][6];
    #pragma unroll
    for (int ct=0; ct<2; ct++){
      int co = ct*16 + n16; if (co > PP-1) co = PP-1;
      #pragma unroll
      for (int k=0;k<6;k++)
        af2[ct][k].i = *(const int4*)(projWb + (size_t)co*CC + k*32 + quad*8);
    }
    floatx4 acc2[2][2];
    #pragma unroll
    for (int ct=0;ct<2;ct++)
      #pragma unroll
      for (int tt=0;tt<2;tt++)
        acc2[ct][tt] = (floatx4){0.f,0.f,0.f,0.f};
    #pragma unroll
    for (int k=0;k<6;k++){
      Frag bf[2];
      #pragma unroll
      for (int tt=0;tt<2;tt++)
        bf[tt].i = *(const int4*)&bufX[(tt*16+n16)*XSTR + k*32 + quad*8];
      #pragma unroll
      for (int ct=0;ct<2;ct++)
        #pragma unroll
        for (int tt=0;tt<2;tt++)
          acc2[ct][tt] = __builtin_amdgcn_mfma_f32_16x16x32_bf16(af2[ct][k].s, bf[tt].s, acc2[ct][tt], 0,0,0);
    }
    #pragma unroll
    for (int ct=0;ct<2;ct++){
      int cobase = ct*16 + quad*4;
      #pragma unroll
      for (int tt=0;tt<2;tt++){
        int t = tt*16 + n16;
        float mv = mk[t0 + t];
        #pragma unroll
        for (int r=0;r<4;r++){
          int co = cobase + r;
          if (co < PP) pro[t*30 + co] = (acc2[ct][tt][r] + projB[co]) * mv;
        }
      }
    }
  }
  __syncthreads();
  // spline on 32 lanes
  if (tid < 32){
    const float scv = 0.07216878364870323f;   // 1/sqrt(192)
    float m = mc;
    float* z0p = z + ((size_t)b*2 + zs)*TTT + tg;
    float* z1p = z + ((size_t)b*2 + (1-zs))*TTT + tg;
    float xs = *z1p;
    float uw[10], uh[10], ud[9];
    #pragma unroll
    for (int k=0;k<10;k++) uw[k]=pro[tl*30+k]*scv;
    #pragma unroll
    for (int k=0;k<10;k++) uh[k]=pro[tl*30+10+k]*scv;
    #pragma unroll
    for (int k=0;k<9;k++)  ud[k]=pro[tl*30+20+k];
    bool inside = (xs >= -5.f) && (xs <= 5.f);
    float xc = fminf(fmaxf(xs,-5.f),5.f);
    float mx=uw[0];
    #pragma unroll
    for (int k=1;k<10;k++) mx=fmaxf(mx,uw[k]);
    float sw=0.f; float wd[10];
    #pragma unroll
    for (int k=0;k<10;k++){ wd[k]=__expf(uw[k]-mx); sw+=wd[k]; }
    float invw = 1.f/sw;
    #pragma unroll
    for (int k=0;k<10;k++) wd[k]=fmaf(0.99f*invw, wd[k], 1e-3f);
    float mh=uh[0];
    #pragma unroll
    for (int k=1;k<10;k++) mh=fmaxf(mh,uh[k]);
    float sh=0.f; float ht[10];
    #pragma unroll
    for (int k=0;k<10;k++){ ht[k]=__expf(uh[k]-mh); sh+=ht[k]; }
    float invh = 1.f/sh;
    #pragma unroll
    for (int k=0;k<10;k++) ht[k]=fmaf(0.99f*invh, ht[k], 1e-3f);
    float cw=-5.f, icw=-5.f, iw=1.f; int idx=0;
    #pragma unroll
    for (int i=0;i<10;i++){
      float nw = (i==9) ? 5.f : fmaf(10.f, wd[i], cw);
      if (cw <= xc){ idx=i; icw=cw; iw=nw-cw; }
      cw=nw;
    }
    float ch=-5.f, ich=-5.f, ih=1.f;
    #pragma unroll
    for (int i=0;i<10;i++){
      float nh = (i==9) ? 5.f : fmaf(10.f, ht[i], ch);
      if (i==idx){ ich=ch; ih=nh-ch; }
      ch=nh;
    }
    const float UDC = logf(expm1f(0.999f));
    float d0=1.f, d1=1.f;
    #pragma unroll
    for (int k=0;k<11;k++){
      float uu = (k==0 || k==10) ? UDC : ud[k-1];
      float dk = 1e-3f + softplus_f(uu);
      if (k==idx)   d0=dk;
      if (k==idx+1) d1=dk;
    }
    float idel = ih/iw;
    float th = (xc-icw)/iw;
    float t1m = th*(1.f-th);
    float den = idel + (d0+d1-2.f*idel)*t1m;
    float outv = ich + ih*(idel*th*th + d0*t1m)/den;
    float omt = 1.f-th;
    float dnum = idel*idel*(d1*th*th + 2.f*idel*t1m + d0*omt*omt);
    float lad = logf(dnum) - 2.f*logf(den);
    float y = inside ? outv : xs;
    lad = inside ? lad : 0.f;
    *z1p = y*m;
    *z0p = (*z0p)*m;
    redS[tid] = lad*m;
  }
  __syncthreads();
  if (tid == 0){
    float ssum = 0.f;
    #pragma unroll
    for (int i=0;i<32;i++) ssum += redS[i];
    atomicAdd(acco + b, -ssum);
  }
}

// ---------------- z init ----------------
__global__ __launch_bounds__(256) void init_z_k(
    const float* __restrict__ e_q, const float* __restrict__ mask,
    const float* __restrict__ pm, const float* __restrict__ pl,
    float* __restrict__ z, float* __restrict__ acc){
  __shared__ float red[256];
  int b = blockIdx.y; int t = blockIdx.x*256 + threadIdx.x;
  float m = mask[(size_t)b*TTT + t];
  float pl0=pl[0], pl1=pl[1];
  float e0 = e_q[((size_t)b*2+0)*TTT + t]*m;
  float e1 = e_q[((size_t)b*2+1)*TTT + t]*m;
  z[((size_t)b*2+0)*TTT + t] = fmaf(__expf(pl0), e0, pm[0])*m;
  z[((size_t)b*2+1)*TTT + t] = fmaf(__expf(pl1), e1, pm[1])*m;
  float contrib = -0.5f*(LOG2PI_F + e0*e0)*m - 0.5f*(LOG2PI_F + e1*e1)*m - (pl0+pl1)*m;
  int tid = threadIdx.x;
  red[tid] = contrib;
  __syncthreads();
  for (int o=128;o>0;o>>=1){ if (tid<o) red[tid]+=red[tid+o]; __syncthreads(); }
  if (tid==0) atomicAdd(acc+b, red[0]);
}

// ---------------- between p-flows and f-flows ----------------
__global__ __launch_bounds__(256) void final_pre_k(
    float* __restrict__ z, const float* __restrict__ w_in, const float* __restrict__ mask,
    const float* __restrict__ am, const float* __restrict__ al, float* __restrict__ acc){
  __shared__ float red[256];
  int b = blockIdx.y; int t = blockIdx.x*256 + threadIdx.x;
  float m = mask[(size_t)b*TTT + t];
  float zu  = z[((size_t)b*2+0)*TTT + t];
  float z1v = z[((size_t)b*2+1)*TTT + t];
  float wv  = w_in[(size_t)b*TTT + t];
  float u  = m / (1.f + __expf(-zu));
  float z0 = (wv - u)*m;
  float y0 = logf(fmaxf(z0, 1e-5f))*m;
  float al0=al[0], al1=al[1];
  z[((size_t)b*2+0)*TTT + t] = fmaf(__expf(al0), y0,  am[0])*m;
  z[((size_t)b*2+1)*TTT + t] = fmaf(__expf(al1), z1v, am[1])*m;
  float contrib = -(logsig_f(zu)+logsig_f(-zu))*m + y0 - (al0+al1)*m;
  int tid = threadIdx.x;
  red[tid] = contrib;
  __syncthreads();
  for (int o=128;o>0;o>>=1){ if (tid<o) red[tid]+=red[tid+o]; __syncthreads(); }
  if (tid==0) atomicAdd(acc+b, red[0]);
}

// ---------------- final 0.5(log2pi + z^2) sum ----------------
__global__ __launch_bounds__(256) void final_post_k(
    const float* __restrict__ z, const float* __restrict__ mask, float* __restrict__ acc){
  __shared__ float red[256];
  int b = blockIdx.y; int t = blockIdx.x*256 + threadIdx.x;
  float m = mask[(size_t)b*TTT + t];
  float z0 = z[((size_t)b*2+0)*TTT + t];
  float z1 = z[((size_t)b*2+1)*TTT + t];
  float contrib = 0.5f*(LOG2PI_F + z0*z0)*m + 0.5f*(LOG2PI_F + z1*z1)*m;
  int tid = threadIdx.x;
  red[tid] = contrib;
  __syncthreads();
  for (int o=128;o>0;o>>=1){ if (tid<o) red[tid]+=red[tid+o]; __syncthreads(); }
  if (tid==0) atomicAdd(acc+b, red[0]);
}

__global__ void write_out_k(const float* __restrict__ acc, float* __restrict__ out, int n){
  int i = threadIdx.x;
  if (i < n) out[i] = acc[i];
}

extern "C" void kernel_launch(void* const* d_in, const int* in_sizes, int n_in,
                              void* d_out, int out_size, void* d_ws, size_t ws_size,
                              hipStream_t stream){
  (void)n_in; (void)out_size; (void)ws_size;
  const float* x         = (const float*)d_in[0];
  const float* mask      = (const float*)d_in[1];
  const float* w_in      = (const float*)d_in[2];
  const float* e_q       = (const float*)d_in[3];
  const float* pre_w     = (const float*)d_in[4];
  const float* pre_b     = (const float*)d_in[5];
  const float* proj_w    = (const float*)d_in[6];
  const float* proj_b    = (const float*)d_in[7];
  const float* dds_dep_w = (const float*)d_in[8];
  const float* dds_dep_b = (const float*)d_in[9];
  const float* dds_pw_w  = (const float*)d_in[10];
  const float* dds_pw_b  = (const float*)d_in[11];
  const float* dds_ln_g  = (const float*)d_in[12];
  const float* dds_ln_b  = (const float*)d_in[13];
  const float* post_pre_w  = (const float*)d_in[14];
  const float* post_pre_b  = (const float*)d_in[15];
  const float* post_proj_w = (const float*)d_in[16];
  const float* post_proj_b = (const float*)d_in[17];
  const float* pdds_dep_w  = (const float*)d_in[18];
  const float* pdds_dep_b  = (const float*)d_in[19];
  const float* pdds_pw_w   = (const float*)d_in[20];
  const float* pdds_pw_b   = (const float*)d_in[21];
  const float* pdds_ln_g   = (const float*)d_in[22];
  const float* pdds_ln_b   = (const float*)d_in[23];
  const float* aff_m    = (const float*)d_in[24];
  const float* aff_logs = (const float*)d_in[25];
  const float* f_pre_w  = (const float*)d_in[26];
  const float* f_pre_b  = (const float*)d_in[27];
  const float* f_dep_w  = (const float*)d_in[28];
  const float* f_dep_b  = (const float*)d_in[29];
  const float* f_pw_w   = (const float*)d_in[30];
  const float* f_pw_b   = (const float*)d_in[31];
  const float* f_ln_g   = (const float*)d_in[32];
  const float* f_ln_b   = (const float*)d_in[33];
  const float* f_proj_w = (const float*)d_in[34];
  const float* f_proj_b = (const float*)d_in[35];
  const float* paff_m    = (const float*)d_in[36];
  const float* paff_logs = (const float*)d_in[37];
  const float* p_pre_w  = (const float*)d_in[38];
  const float* p_pre_b  = (const float*)d_in[39];
  const float* p_dep_w  = (const float*)d_in[40];
  const float* p_dep_b  = (const float*)d_in[41];
  const float* p_pw_w   = (const float*)d_in[42];
  const float* p_pw_b   = (const float*)d_in[43];
  const float* p_ln_g   = (const float*)d_in[44];
  const float* p_ln_b   = (const float*)d_in[45];
  const float* p_proj_w = (const float*)d_in[46];
  const float* p_proj_b = (const float*)d_in[47];

  int Bn = in_sizes[0] / (CC*TTT);
  size_t big = (size_t)Bn*CC*TTT;
  float* A    = (float*)d_ws;
  float* Bb   = A + big;
  float* H    = Bb + big;
  float* GP   = H + big;
  float* zbuf = GP + big;
  float* acc  = zbuf + (size_t)Bn*2*TTT;
  unsigned short* Wb = (unsigned short*)(acc + ((Bn + 3) & ~3));

  hipMemsetAsync(acc, 0, Bn*sizeof(float), stream);
  convert_w_k<<<(33*WSLOT + 8*PSLOT + 255)/256, 256, 0, stream>>>(
      pre_w, proj_w, post_proj_w, dds_pw_w, pdds_pw_w, p_pw_w, f_pw_w,
      p_proj_w, f_proj_w, Wb);

  dim3 g32(TTT/32, Bn), g256(TTT/256, Bn);
  dim3 b256(256);

  unsigned short* W_pre      = Wb + 0*(size_t)WSLOT;
  unsigned short* W_proj     = Wb + 1*(size_t)WSLOT;
  unsigned short* W_postproj = Wb + 2*(size_t)WSLOT;
  unsigned short* W_dds      = Wb + 3*(size_t)WSLOT;
  unsigned short* W_pdds     = Wb + 6*(size_t)WSLOT;
  unsigned short* W_ppw      = Wb + 9*(size_t)WSLOT;
  unsigned short* W_fpw      = Wb + 21*(size_t)WSLOT;
  unsigned short* W_pproj    = Wb + 33*(size_t)WSLOT;
  unsigned short* W_fproj    = W_pproj + 4*(size_t)PSLOT;

  const int dils[3] = {1,3,9};

  auto layer = [&](const float* bin, float* bout,
                   const float* src1, int s1s, const float* pw1, const float* pb1,
                   const float* gptr, int srcmode, int outmode,
                   const float* dep_w, const float* dep_b, unsigned short* Ws,
                   const float* pw_b, const float* ln_g, const float* ln_b, int li,
                   const unsigned short* projWb, const float* projB, float* zp, int zs){
    dds_fused_k<<<g32, b256, 0, stream>>>(
      bin, src1, s1s, pw1, pb1, gptr, bout, mask,
      dep_w + (size_t)li*CC*3, dep_b + (size_t)li*CC,
      ln_g + (size_t)(li*2+0)*CC, ln_b + (size_t)(li*2+0)*CC,
      Ws + (size_t)li*WSLOT, pw_b + (size_t)li*CC,
      ln_g + (size_t)(li*2+1)*CC, ln_b + (size_t)(li*2+1)*CC,
      dils[li], srcmode, outmode, projWb, projB, zp, zs, acc);
  };

  // ---- h path ----
  conv_cc_k<<<g32, b256, 0, stream>>>(x, W_pre, pre_b, mask, nullptr, A, 0);
  layer(A, Bb, nullptr,0,nullptr,nullptr,nullptr, 0,0, dds_dep_w, dds_dep_b, W_dds, dds_pw_b, dds_ln_g, dds_ln_b, 0, nullptr,nullptr,nullptr,0);
  layer(Bb, A, nullptr,0,nullptr,nullptr,nullptr, 0,0, dds_dep_w, dds_dep_b, W_dds, dds_pw_b, dds_ln_g, dds_ln_b, 1, nullptr,nullptr,nullptr,0);
  layer(A, Bb, nullptr,0,nullptr,nullptr,nullptr, 0,0, dds_dep_w, dds_dep_b, W_dds, dds_pw_b, dds_ln_g, dds_ln_b, 2, nullptr,nullptr,nullptr,0);
  conv_cc_k<<<g32, b256, 0, stream>>>(Bb, W_proj, proj_b, mask, nullptr, H, 1);

  // ---- hw path ----
  layer(nullptr, A, w_in, TTT, post_pre_w, post_pre_b, nullptr, 1,0, pdds_dep_w, pdds_dep_b, W_pdds, pdds_pw_b, pdds_ln_g, pdds_ln_b, 0, nullptr,nullptr,nullptr,0);
  layer(A, Bb, nullptr,0,nullptr,nullptr,nullptr, 0,0, pdds_dep_w, pdds_dep_b, W_pdds, pdds_pw_b, pdds_ln_g, pdds_ln_b, 1, nullptr,nullptr,nullptr,0);
  layer(Bb, A, nullptr,0,nullptr,nullptr,nullptr, 0,0, pdds_dep_w, pdds_dep_b, W_pdds, pdds_pw_b, pdds_ln_g, pdds_ln_b, 2, nullptr,nullptr,nullptr,0);
  conv_cc_k<<<g32, b256, 0, stream>>>(A, W_postproj, post_proj_b, mask, H, GP, 2);

  // ---- init z ----
  init_z_k<<<g256, b256, 0, stream>>>(e_q, mask, paff_m, paff_logs, zbuf, acc);

  // ---- 4 posterior flows (g = GP) ----
  for (int f=0; f<4; f++){
    int s = f & 1;
    const float* dep_w = p_dep_w + (size_t)f*3*CC*3;
    const float* dep_b = p_dep_b + (size_t)f*3*CC;
    unsigned short* Ws = W_ppw + (size_t)f*3*WSLOT;
    const float* pw_b  = p_pw_b + (size_t)f*3*CC;
    const float* ln_g  = p_ln_g + (size_t)f*3*2*CC;
    const float* ln_b  = p_ln_b + (size_t)f*3*2*CC;
    layer(nullptr, A, zbuf + (size_t)s*TTT, 2*TTT, p_pre_w + (size_t)f*CC, p_pre_b + (size_t)f*CC, GP, 1,0, dep_w, dep_b, Ws, pw_b, ln_g, ln_b, 0, nullptr,nullptr,nullptr,0);
    layer(A, Bb, nullptr,0,nullptr,nullptr,nullptr, 0,0, dep_w, dep_b, Ws, pw_b, ln_g, ln_b, 1, nullptr,nullptr,nullptr,0);
    layer(Bb, nullptr, nullptr,0,nullptr,nullptr,nullptr, 0,1, dep_w, dep_b, Ws, pw_b, ln_g, ln_b, 2,
          W_pproj + (size_t)f*PSLOT, p_proj_b + (size_t)f*PP, zbuf, s);
  }

  // ---- transition ----
  final_pre_k<<<g256, b256, 0, stream>>>(zbuf, w_in, mask, aff_m, aff_logs, acc);

  // ---- 4 flows (g = H) ----
  for (int f=0; f<4; f++){
    int s = f & 1;
    const float* dep_w = f_dep_w + (size_t)f*3*CC*3;
    const float* dep_b = f_dep_b + (size_t)f*3*CC;
    unsigned short* Ws = W_fpw + (size_t)f*3*WSLOT;
    const float* pw_b  = f_pw_b + (size_t)f*3*CC;
    const float* ln_g  = f_ln_g + (size_t)f*3*2*CC;
    const float* ln_b  = f_ln_b + (size_t)f*3*2*CC;
    layer(nullptr, A, zbuf + (size_t)s*TTT, 2*TTT, f_pre_w + (size_t)f*CC, f_pre_b + (size_t)f*CC, H, 1,0, dep_w, dep_b, Ws, pw_b, ln_g, ln_b, 0, nullptr,nullptr,nullptr,0);
    layer(A, Bb, nullptr,0,nullptr,nullptr,nullptr, 0,0, dep_w, dep_b, Ws, pw_b, ln_g, ln_b, 1, nullptr,nullptr,nullptr,0);
    layer(Bb, nullptr, nullptr,0,nullptr,nullptr,nullptr, 0,1, dep_w, dep_b, Ws, pw_b, ln_g, ln_b, 2,
          W_fproj + (size_t)f*PSLOT, f_proj_b + (size_t)f*PP, zbuf, s);
  }

  final_post_k<<<g256, b256, 0, stream>>>(zbuf, mask, acc);
  write_out_k<<<1, 64, 0, stream>>>(acc, (float*)d_out, Bn);
}

// Round 5
// 1185.941 us; speedup vs baseline: 1.0741x; 1.0741x over previous
//
#include <hip/hip_runtime.h>
#include <math.h>

#define CC 192
#define TTT 768
#define PP 29
#define LOG2PI_F 1.8378770664093453f
#define WSLOT 36864   // swizzled 192x192 slot (elements)
#define PSW 6144      // swizzled 32x192 proj slot (elements)
#define XS 200        // ushort stride for [t][c] bf16 LDS tiles (400B rows, 16B-aligned)

typedef __attribute__((ext_vector_type(8))) short short8;
typedef __attribute__((ext_vector_type(4))) float floatx4;
union Frag { int4 i; short8 s; };

__device__ __forceinline__ float geluf(float x){
  float u = 1.5957691216057308f * (x + 0.044715f*x*x*x);
  return x * __builtin_amdgcn_rcpf(1.f + __expf(-u));
}
__device__ __forceinline__ float softplus_f(float x){
  return (x > 20.f) ? x : log1pf(__expf(x));
}
__device__ __forceinline__ float logsig_f(float x){
  return -softplus_f(-x);
}
__device__ __forceinline__ unsigned short f2bf(float f){
  unsigned int u = __builtin_bit_cast(unsigned int, f);
  u += 0x7fffu + ((u >> 16) & 1u);
  return (unsigned short)(u >> 16);
}
__device__ __forceinline__ unsigned int packbf2(float a0, float a1){
  return (unsigned int)f2bf(a0) | ((unsigned int)f2bf(a1) << 16);
}
__device__ __forceinline__ void unbf2(unsigned int u, float& lo, float& hi){
  lo = __builtin_bit_cast(float, u << 16);
  hi = __builtin_bit_cast(float, u & 0xffff0000u);
}
__device__ __forceinline__ void unp8(int4 v, float* o){
  unsigned int* p = (unsigned int*)&v;
  unbf2(p[0], o[0], o[1]); unbf2(p[1], o[2], o[3]);
  unbf2(p[2], o[4], o[5]); unbf2(p[3], o[6], o[7]);
}

// ---------------- weight f32 -> bf16 swizzled fragment order ----------------
// conv slot layout: Wsw[((tile*6 + k)*64 + lane)*8 + e] = W[tile*16 + (lane&15)][k*32 + (lane>>4)*8 + e]
__global__ __launch_bounds__(256) void convert_w_k(
    const float* __restrict__ p0, const float* __restrict__ p1,
    const float* __restrict__ p2, const float* __restrict__ p3,
    const float* __restrict__ p4, const float* __restrict__ p5,
    const float* __restrict__ p6, const float* __restrict__ p7,
    const float* __restrict__ p8, unsigned short* __restrict__ Wb){
  int i = blockIdx.x*256 + threadIdx.x;
  const int totalA = 33*WSLOT;
  const int total = totalA + 8*PSW;
  if (i >= total) return;
  if (i < totalA){
    int slot = i / WSLOT, j = i % WSLOT;
    int e = j & 7, lane = (j>>3) & 63, kt = j >> 9;
    int k = kt % 6, tile = kt / 6;
    int co = tile*16 + (lane & 15);
    int kk = k*32 + (lane>>4)*8 + e;
    int r = co*CC + kk;
    const float* src;
    if      (slot == 0) src = p0 + r;
    else if (slot == 1) src = p1 + r;
    else if (slot == 2) src = p2 + r;
    else if (slot < 6)  src = p3 + (size_t)(slot-3)*WSLOT + r;
    else if (slot < 9)  src = p4 + (size_t)(slot-6)*WSLOT + r;
    else if (slot < 21) src = p5 + (size_t)(slot-9)*WSLOT + r;
    else                src = p6 + (size_t)(slot-21)*WSLOT + r;
    Wb[i] = f2bf(*src);
  } else {
    int r2 = i - totalA;
    int ps = r2 / PSW, j = r2 % PSW;
    int e = j & 7, lane = (j>>3) & 63, kt = j >> 9;
    int k = kt % 6, tile = kt / 6;
    int co = tile*16 + (lane & 15); if (co > PP-1) co = PP-1;
    int kk = k*32 + (lane>>4)*8 + e;
    const float* base = (ps < 4) ? (p7 + (size_t)ps*PP*CC) : (p8 + (size_t)(ps-4)*PP*CC);
    Wb[i] = f2bf(base[co*CC + kk]);
  }
}

// ---------------- x f32 [B][C][T] -> bf16 [B][T][C] ----------------
__global__ __launch_bounds__(256) void transpose_x_k(
    const float* __restrict__ x, unsigned short* __restrict__ xT){
  __shared__ unsigned short tile[32*XS];
  int b = blockIdx.y, t0 = blockIdx.x*32, tid = threadIdx.x;
  int tl4 = (tid & 7)*4, cr = tid >> 3;
  #pragma unroll
  for (int rnd=0; rnd<6; rnd++){
    int c = rnd*32 + cr;
    float4 v4 = *(const float4*)(x + ((size_t)b*CC + c)*TTT + t0 + tl4);
    tile[(tl4+0)*XS + c] = f2bf(v4.x);
    tile[(tl4+1)*XS + c] = f2bf(v4.y);
    tile[(tl4+2)*XS + c] = f2bf(v4.z);
    tile[(tl4+3)*XS + c] = f2bf(v4.w);
  }
  __syncthreads();
  #pragma unroll
  for (int k=0;k<3;k++){
    int task = k*256 + tid;
    int row = task/24, cn = task%24;
    *(int4*)(xT + ((size_t)b*TTT + t0 + row)*CC + cn*8) = *(const int4*)&tile[row*XS + cn*8];
  }
}

// ---------------- conv 192x192 bf16 MFMA, t-major bf16 in/out ----------------
// mode 0: out=acc+bias ; mode 1: *mask ; mode 2: *mask + addsrc(bf16)
__global__ __launch_bounds__(256) void conv_cc_k(
    const unsigned short* __restrict__ in, const unsigned short* __restrict__ Wsw,
    const float* __restrict__ bias, const float* __restrict__ mask,
    const unsigned short* __restrict__ addsrc, unsigned short* __restrict__ outb, int mode){
  __shared__ unsigned short bufX[32*XS];
  __shared__ unsigned short bufY[32*XS];
  __shared__ float marr[32];
  int b = blockIdx.y, t0 = blockIdx.x*32, tid = threadIdx.x;
  #pragma unroll
  for (int k=0;k<3;k++){
    int task = k*256 + tid;
    int row = task/24, cn = task%24;
    const unsigned short* src = in + ((size_t)b*TTT + t0 + row)*CC + cn*8;
    *(int4*)&bufX[row*XS + cn*8] = *(const int4*)src;
    if (mode == 2){
      const unsigned short* s2 = addsrc + ((size_t)b*TTT + t0 + row)*CC + cn*8;
      *(int4*)&bufY[row*XS + cn*8] = *(const int4*)s2;
    }
  }
  if (tid >= 128 && tid < 160) marr[tid-128] = mask[(size_t)b*TTT + t0 + (tid-128)];
  __syncthreads();
  int w = tid >> 6, lane = tid & 63;
  int n16 = lane & 15, quad = lane >> 4;
  Frag af[3][6];
  #pragma unroll
  for (int ct=0; ct<3; ct++){
    int tile = w*3 + ct;
    #pragma unroll
    for (int k=0;k<6;k++)
      af[ct][k].i = *(const int4*)(Wsw + ((size_t)(tile*6 + k)*64 + lane)*8);
  }
  floatx4 acc[3][2];
  #pragma unroll
  for (int ct=0;ct<3;ct++)
    #pragma unroll
    for (int tt=0;tt<2;tt++)
      acc[ct][tt] = (floatx4){0.f,0.f,0.f,0.f};
  #pragma unroll
  for (int k=0;k<6;k++){
    Frag bf[2];
    #pragma unroll
    for (int tt=0;tt<2;tt++)
      bf[tt].i = *(const int4*)&bufX[(tt*16+n16)*XS + k*32 + quad*8];
    #pragma unroll
    for (int ct=0;ct<3;ct++)
      #pragma unroll
      for (int tt=0;tt<2;tt++)
        acc[ct][tt] = __builtin_amdgcn_mfma_f32_16x16x32_bf16(af[ct][k].s, bf[tt].s, acc[ct][tt], 0,0,0);
  }
  __syncthreads();   // all MFMA reads of bufX done before overwrite
  #pragma unroll
  for (int ct=0;ct<3;ct++){
    int cobase = w*48 + ct*16 + quad*4;
    float4 b4 = *(const float4*)(bias + cobase);
    float ba[4] = {b4.x, b4.y, b4.z, b4.w};
    #pragma unroll
    for (int tt=0;tt<2;tt++){
      int t = tt*16 + n16;
      float mv = (mode >= 1) ? marr[t] : 1.f;
      float av[4] = {0.f,0.f,0.f,0.f};
      if (mode == 2){
        uint2 uy = *(uint2*)&bufY[t*XS + cobase];
        unbf2(uy.x, av[0], av[1]); unbf2(uy.y, av[2], av[3]);
      }
      float hh[4];
      #pragma unroll
      for (int r=0;r<4;r++){
        float v = acc[ct][tt][r] + ba[r];
        if (mode >= 1) v *= mv;
        if (mode == 2) v += av[r];
        hh[r] = v;
      }
      uint2 wv; wv.x = packbf2(hh[0], hh[1]); wv.y = packbf2(hh[2], hh[3]);
      *(uint2*)&bufX[t*XS + cobase] = wv;
    }
  }
  __syncthreads();
  #pragma unroll
  for (int k=0;k<3;k++){
    int task = k*256 + tid;
    int row = task/24, cn = task%24;
    *(int4*)(outb + ((size_t)b*TTT + t0 + row)*CC + cn*8) = *(const int4*)&bufX[row*XS + cn*8];
  }
}

// ---------------- mega DDS: 3 fused layers (+ optional proj+spline) ----------------
// srcmode 0: x from `in` (bf16 t-major); srcmode 1: x = pw1*z + pb1 (+ g)
// outmode 0: write center 32 rows to outb; outmode 1: proj + RQS spline
__global__ __launch_bounds__(256) void mega_dds_k(
    const unsigned short* __restrict__ in,
    const float* __restrict__ zsrc, int zstride,
    const unsigned short* __restrict__ g,
    unsigned short* __restrict__ outb,
    const float* __restrict__ mask,
    const float* __restrict__ dwB, const float* __restrict__ dbB,
    const float* __restrict__ lngB, const float* __restrict__ lnbB,
    const float* __restrict__ pwbB,
    const float* __restrict__ pw1, const float* __restrict__ pb1,
    const unsigned short* __restrict__ Wsw,
    int srcmode, int outmode,
    const unsigned short* __restrict__ projW, const float* __restrict__ projB,
    float* __restrict__ z, int zs, float* __restrict__ acco){
  __shared__ unsigned short ping[64*XS];   // layer stream (x -> h), in-place residual update
  __shared__ unsigned short pong[64*XS];   // gelu'd conv input scratch
  __shared__ float par[1728];              // dw(576) db g0 b0 g1 b1 pb
  __shared__ float redS[64*17], redQ[64*17];
  __shared__ float mst[64], rst[64];
  __shared__ float mrow[64], zwin[64];
  __shared__ float pw1s[CC], pb1s[CC];
  __shared__ float pro[32*30];
  __shared__ float sred[64];

  int b = blockIdx.y, t0 = blockIdx.x*32, tid = threadIdx.x;
  int ws0 = t0 - 16;
  int w = tid >> 6, lane = tid & 63;
  int n16 = lane & 15, quad = lane >> 4;
  const int dils[3] = {1,3,9};

  // ---- S0: masks, z window, rank1 params, layer-0 params ----
  if (tid < 64){
    int gt = ws0 + tid;
    bool inr = (gt >= 0) && (gt < TTT);
    int gc = gt < 0 ? 0 : (gt > TTT-1 ? TTT-1 : gt);
    mrow[tid] = inr ? mask[(size_t)b*TTT + gc] : 0.f;
    zwin[tid] = (srcmode == 1 && inr) ? zsrc[(size_t)b*zstride + gc] : 0.f;
  }
  if (srcmode == 1 && tid < 192){ pw1s[tid] = pw1[tid]; pb1s[tid] = pb1[tid]; }
  {
    const float* dwl = dwB;
    for (int i2=tid; i2<576; i2+=256) par[i2] = dwl[i2];
    if (tid < 192){
      par[576+tid]  = dbB[tid];
      par[768+tid]  = lngB[tid];
      par[960+tid]  = lnbB[tid];
      par[1152+tid] = lngB[CC+tid];
      par[1344+tid] = lnbB[CC+tid];
      par[1536+tid] = pwbB[tid];
    }
  }
  __syncthreads();

  // ---- S1: stage x window into ping (bf16 [64][192]) ----
  if (srcmode == 0){
    #pragma unroll
    for (int k=0;k<6;k++){
      int task = k*256 + tid;
      if (task < 1536){
        int row = task/24, cn = task%24;
        int gt = ws0 + row; gt = gt < 0 ? 0 : (gt > TTT-1 ? TTT-1 : gt);
        *(int4*)&ping[row*XS + cn*8] = *(const int4*)(in + ((size_t)b*TTT + gt)*CC + cn*8);
      }
    }
  } else {
    #pragma unroll
    for (int k=0;k<6;k++){
      int task = k*256 + tid;
      if (task < 1536){
        int row = task/24, cn = task%24;
        int gt = ws0 + row; int gc = gt < 0 ? 0 : (gt > TTT-1 ? TTT-1 : gt);
        float zv = zwin[row];
        float hv[8];
        if (g){
          int4 gg = *(const int4*)(g + ((size_t)b*TTT + gc)*CC + cn*8);
          unp8(gg, hv);
        } else {
          #pragma unroll
          for (int e=0;e<8;e++) hv[e] = 0.f;
        }
        int c0 = cn*8;
        unsigned int ww[4];
        #pragma unroll
        for (int e2=0;e2<4;e2++){
          float a0 = hv[2*e2]   + fmaf(pw1s[c0+2*e2],   zv, pb1s[c0+2*e2]);
          float a1 = hv[2*e2+1] + fmaf(pw1s[c0+2*e2+1], zv, pb1s[c0+2*e2+1]);
          ww[e2] = packbf2(a0, a1);
        }
        *(int4*)&ping[row*XS + c0] = *(int4*)ww;
      }
    }
  }
  __syncthreads();

  // ---- 3 fused layers ----
  for (int l=0; l<3; l++){
    int dil = dils[l];
    // P1: depthwise from ping; thread = (row i = lane-ish over 64, cgroup w of 48 ch)
    int i = tid & 63, cg = tid >> 6;
    int c0 = cg*48;
    int iL = i - dil; int iLc = iL < 0 ? 0 : iL;
    int iR = i + dil; int iRc = iR > 63 ? 63 : iR;
    float ml = (iL >= 0) ? mrow[iLc] : 0.f;
    float mc = mrow[i];
    float mr = (iR <= 63) ? mrow[iRc] : 0.f;
    float v[48];
    float s = 0.f, q = 0.f;
    #pragma unroll
    for (int j=0;j<6;j++){
      int c = c0 + j*8;
      float xl[8], xc[8], xr[8];
      unp8(*(const int4*)&ping[iLc*XS + c], xl);
      unp8(*(const int4*)&ping[i  *XS + c], xc);
      unp8(*(const int4*)&ping[iRc*XS + c], xr);
      #pragma unroll
      for (int e=0;e<8;e++){
        int cc = c + e;
        float val = fmaf(par[cc*3], xl[e]*ml, fmaf(par[cc*3+1], xc[e]*mc,
                    fmaf(par[cc*3+2], xr[e]*mr, par[576+cc])));
        v[j*8+e] = val; s += val; q = fmaf(val, val, q);
      }
    }
    redS[i*17 + cg] = s; redQ[i*17 + cg] = q;
    __syncthreads();
    if (tid < 64){
      float S=0.f, Q=0.f;
      #pragma unroll
      for (int j=0;j<4;j++){ S += redS[tid*17+j]; Q += redQ[tid*17+j]; }
      float m = S*(1.f/CC);
      mst[tid] = m; rst[tid] = rsqrtf(Q*(1.f/CC) - m*m + 1e-5f);
    }
    __syncthreads();
    // P3: LN + gelu -> pong
    {
      float mm = mst[i], rr = rst[i];
      #pragma unroll
      for (int j=0;j<6;j++){
        int c = c0 + j*8;
        unsigned int ww[4];
        #pragma unroll
        for (int e2=0;e2<4;e2++){
          float a0 = geluf((v[j*8+2*e2]  -mm)*rr*par[768+c+2*e2]   + par[960+c+2*e2]);
          float a1 = geluf((v[j*8+2*e2+1]-mm)*rr*par[768+c+2*e2+1] + par[960+c+2*e2+1]);
          ww[e2] = packbf2(a0, a1);
        }
        *(int4*)&pong[i*XS + c] = *(int4*)ww;
      }
    }
    __syncthreads();
    // P4: conv via MFMA; wave w owns co-tiles w*3..w*3+2, all 4 t-tiles
    floatx4 acc4[3][4];
    {
      Frag af[3][6];
      const unsigned short* WL = Wsw + (size_t)l*WSLOT;
      #pragma unroll
      for (int ct=0; ct<3; ct++){
        int tile = w*3 + ct;
        #pragma unroll
        for (int k=0;k<6;k++)
          af[ct][k].i = *(const int4*)(WL + ((size_t)(tile*6 + k)*64 + lane)*8);
      }
      #pragma unroll
      for (int ct=0;ct<3;ct++)
        #pragma unroll
        for (int tt=0;tt<4;tt++)
          acc4[ct][tt] = (floatx4){0.f,0.f,0.f,0.f};
      #pragma unroll
      for (int k=0;k<6;k++){
        Frag bf[4];
        #pragma unroll
        for (int tt=0;tt<4;tt++)
          bf[tt].i = *(const int4*)&pong[(tt*16+n16)*XS + k*32 + quad*8];
        #pragma unroll
        for (int ct=0;ct<3;ct++)
          #pragma unroll
          for (int tt=0;tt<4;tt++)
            acc4[ct][tt] = __builtin_amdgcn_mfma_f32_16x16x32_bf16(af[ct][k].s, bf[tt].s, acc4[ct][tt], 0,0,0);
      }
    }
    // bias + per-row partial stats
    #pragma unroll
    for (int ct=0;ct<3;ct++){
      int cobase = w*48 + ct*16 + quad*4;
      #pragma unroll
      for (int tt=0;tt<4;tt++)
        #pragma unroll
        for (int r=0;r<4;r++)
          acc4[ct][tt][r] += par[1536+cobase+r];
    }
    #pragma unroll
    for (int tt=0;tt<4;tt++){
      float ps=0.f, pq=0.f;
      #pragma unroll
      for (int ct=0;ct<3;ct++)
        #pragma unroll
        for (int r=0;r<4;r++){ float vv = acc4[ct][tt][r]; ps += vv; pq = fmaf(vv,vv,pq); }
      int row = tt*16 + n16;
      redS[row*17 + (w*4+quad)] = ps;
      redQ[row*17 + (w*4+quad)] = pq;
    }
    __syncthreads();
    if (tid < 64){
      float S=0.f, Q=0.f;
      #pragma unroll
      for (int j=0;j<16;j++){ S += redS[tid*17+j]; Q += redQ[tid*17+j]; }
      float m = S*(1.f/CC);
      mst[tid] = m; rst[tid] = rsqrtf(Q*(1.f/CC) - m*m + 1e-5f);
    }
    __syncthreads();
    // P6: LN + gelu + residual, in-place into ping (each element owned by one lane)
    #pragma unroll
    for (int ct=0;ct<3;ct++){
      int cobase = w*48 + ct*16 + quad*4;
      #pragma unroll
      for (int tt=0;tt<4;tt++){
        int row = tt*16 + n16;
        float mm = mst[row], rr = rst[row];
        uint2 ux = *(uint2*)&ping[row*XS + cobase];
        float x0,x1,x2,x3;
        unbf2(ux.x, x0, x1); unbf2(ux.y, x2, x3);
        float xa[4] = {x0,x1,x2,x3};
        float hh[4];
        #pragma unroll
        for (int r=0;r<4;r++){
          float val = (acc4[ct][tt][r] - mm)*rr*par[1152+cobase+r] + par[1344+cobase+r];
          hh[r] = xa[r] + geluf(val);
        }
        uint2 wv; wv.x = packbf2(hh[0], hh[1]); wv.y = packbf2(hh[2], hh[3]);
        *(uint2*)&ping[row*XS + cobase] = wv;
      }
    }
    __syncthreads();
    // stage next layer's params
    if (l < 2){
      int ln = l+1;
      const float* dwl = dwB + (size_t)ln*CC*3;
      for (int i2=tid; i2<576; i2+=256) par[i2] = dwl[i2];
      if (tid < 192){
        par[576+tid]  = dbB[ln*CC+tid];
        par[768+tid]  = lngB[(ln*2+0)*CC+tid];
        par[960+tid]  = lnbB[(ln*2+0)*CC+tid];
        par[1152+tid] = lngB[(ln*2+1)*CC+tid];
        par[1344+tid] = lnbB[(ln*2+1)*CC+tid];
        par[1536+tid] = pwbB[ln*CC+tid];
      }
      __syncthreads();
    }
  }

  if (outmode == 0){
    // write center 32 rows
    #pragma unroll
    for (int k=0;k<3;k++){
      int task = k*256 + tid;
      int row = task/24, cn = task%24;
      *(int4*)(outb + ((size_t)b*TTT + t0 + row)*CC + cn*8) = *(const int4*)&ping[(16+row)*XS + cn*8];
    }
    return;
  }

  // ---- proj (29x192) on center 32 rows: waves 0,1 ----
  if (w < 2){
    Frag pf[2][6];
    #pragma unroll
    for (int ct2=0; ct2<2; ct2++)
      #pragma unroll
      for (int k=0;k<6;k++)
        pf[ct2][k].i = *(const int4*)(projW + ((size_t)(ct2*6 + k)*64 + lane)*8);
    floatx4 acc2[2];
    acc2[0] = (floatx4){0.f,0.f,0.f,0.f};
    acc2[1] = (floatx4){0.f,0.f,0.f,0.f};
    #pragma unroll
    for (int k=0;k<6;k++){
      Frag bf;
      bf.i = *(const int4*)&ping[(16 + w*16 + n16)*XS + k*32 + quad*8];
      #pragma unroll
      for (int ct2=0;ct2<2;ct2++)
        acc2[ct2] = __builtin_amdgcn_mfma_f32_16x16x32_bf16(pf[ct2][k].s, bf.s, acc2[ct2], 0,0,0);
    }
    #pragma unroll
    for (int ct2=0;ct2<2;ct2++){
      int cobase = ct2*16 + quad*4;
      int rt = w*16 + n16;
      float mv = mrow[16+rt];
      #pragma unroll
      for (int r=0;r<4;r++){
        int co = cobase + r;
        if (co < PP) pro[rt*30 + co] = (acc2[ct2][r] + projB[co]) * mv;
      }
    }
  }
  __syncthreads();
  // ---- RQS spline on 32 lanes ----
  if (tid < 32){
    const float scv = 0.07216878364870323f;   // 1/sqrt(192)
    int tg = t0 + tid;
    float m = mrow[16+tid];
    float* z0p = z + ((size_t)b*2 + zs)*TTT + tg;
    float* z1p = z + ((size_t)b*2 + (1-zs))*TTT + tg;
    float xs = *z1p;
    float uw[10], uh[10], ud[9];
    #pragma unroll
    for (int k=0;k<10;k++) uw[k]=pro[tid*30+k]*scv;
    #pragma unroll
    for (int k=0;k<10;k++) uh[k]=pro[tid*30+10+k]*scv;
    #pragma unroll
    for (int k=0;k<9;k++)  ud[k]=pro[tid*30+20+k];
    bool inside = (xs >= -5.f) && (xs <= 5.f);
    float xc = fminf(fmaxf(xs,-5.f),5.f);
    float mx=uw[0];
    #pragma unroll
    for (int k=1;k<10;k++) mx=fmaxf(mx,uw[k]);
    float sw=0.f; float wd[10];
    #pragma unroll
    for (int k=0;k<10;k++){ wd[k]=__expf(uw[k]-mx); sw+=wd[k]; }
    float invw = 1.f/sw;
    #pragma unroll
    for (int k=0;k<10;k++) wd[k]=fmaf(0.99f*invw, wd[k], 1e-3f);
    float mh=uh[0];
    #pragma unroll
    for (int k=1;k<10;k++) mh=fmaxf(mh,uh[k]);
    float sh=0.f; float ht[10];
    #pragma unroll
    for (int k=0;k<10;k++){ ht[k]=__expf(uh[k]-mh); sh+=ht[k]; }
    float invh = 1.f/sh;
    #pragma unroll
    for (int k=0;k<10;k++) ht[k]=fmaf(0.99f*invh, ht[k], 1e-3f);
    float cw=-5.f, icw=-5.f, iw=1.f; int idx=0;
    #pragma unroll
    for (int i2=0;i2<10;i2++){
      float nw = (i2==9) ? 5.f : fmaf(10.f, wd[i2], cw);
      if (cw <= xc){ idx=i2; icw=cw; iw=nw-cw; }
      cw=nw;
    }
    float ch=-5.f, ich=-5.f, ih=1.f;
    #pragma unroll
    for (int i2=0;i2<10;i2++){
      float nh = (i2==9) ? 5.f : fmaf(10.f, ht[i2], ch);
      if (i2==idx){ ich=ch; ih=nh-ch; }
      ch=nh;
    }
    const float UDC = logf(expm1f(0.999f));
    float d0=1.f, d1=1.f;
    #pragma unroll
    for (int k=0;k<11;k++){
      float uu = (k==0 || k==10) ? UDC : ud[k-1];
      float dk = 1e-3f + softplus_f(uu);
      if (k==idx)   d0=dk;
      if (k==idx+1) d1=dk;
    }
    float idel = ih/iw;
    float th = (xc-icw)/iw;
    float t1m = th*(1.f-th);
    float den = idel + (d0+d1-2.f*idel)*t1m;
    float outv = ich + ih*(idel*th*th + d0*t1m)/den;
    float omt = 1.f-th;
    float dnum = idel*idel*(d1*th*th + 2.f*idel*t1m + d0*omt*omt);
    float lad = logf(dnum) - 2.f*logf(den);
    float y = inside ? outv : xs;
    lad = inside ? lad : 0.f;
    *z1p = y*m;
    *z0p = (*z0p)*m;
    sred[tid] = lad*m;
  }
  __syncthreads();
  if (tid == 0){
    float ssum = 0.f;
    #pragma unroll
    for (int i2=0;i2<32;i2++) ssum += sred[i2];
    atomicAdd(acco + b, -ssum);
  }
}

// ---------------- z init ----------------
__global__ __launch_bounds__(256) void init_z_k(
    const float* __restrict__ e_q, const float* __restrict__ mask,
    const float* __restrict__ pm, const float* __restrict__ pl,
    float* __restrict__ z, float* __restrict__ acc){
  __shared__ float red[256];
  int b = blockIdx.y; int t = blockIdx.x*256 + threadIdx.x;
  float m = mask[(size_t)b*TTT + t];
  float pl0=pl[0], pl1=pl[1];
  float e0 = e_q[((size_t)b*2+0)*TTT + t]*m;
  float e1 = e_q[((size_t)b*2+1)*TTT + t]*m;
  z[((size_t)b*2+0)*TTT + t] = fmaf(__expf(pl0), e0, pm[0])*m;
  z[((size_t)b*2+1)*TTT + t] = fmaf(__expf(pl1), e1, pm[1])*m;
  float contrib = -0.5f*(LOG2PI_F + e0*e0)*m - 0.5f*(LOG2PI_F + e1*e1)*m - (pl0+pl1)*m;
  int tid = threadIdx.x;
  red[tid] = contrib;
  __syncthreads();
  for (int o=128;o>0;o>>=1){ if (tid<o) red[tid]+=red[tid+o]; __syncthreads(); }
  if (tid==0) atomicAdd(acc+b, red[0]);
}

// ---------------- between p-flows and f-flows ----------------
__global__ __launch_bounds__(256) void final_pre_k(
    float* __restrict__ z, const float* __restrict__ w_in, const float* __restrict__ mask,
    const float* __restrict__ am, const float* __restrict__ al, float* __restrict__ acc){
  __shared__ float red[256];
  int b = blockIdx.y; int t = blockIdx.x*256 + threadIdx.x;
  float m = mask[(size_t)b*TTT + t];
  float zu  = z[((size_t)b*2+0)*TTT + t];
  float z1v = z[((size_t)b*2+1)*TTT + t];
  float wv  = w_in[(size_t)b*TTT + t];
  float u  = m / (1.f + __expf(-zu));
  float z0 = (wv - u)*m;
  float y0 = logf(fmaxf(z0, 1e-5f))*m;
  float al0=al[0], al1=al[1];
  z[((size_t)b*2+0)*TTT + t] = fmaf(__expf(al0), y0,  am[0])*m;
  z[((size_t)b*2+1)*TTT + t] = fmaf(__expf(al1), z1v, am[1])*m;
  float contrib = -(logsig_f(zu)+logsig_f(-zu))*m + y0 - (al0+al1)*m;
  int tid = threadIdx.x;
  red[tid] = contrib;
  __syncthreads();
  for (int o=128;o>0;o>>=1){ if (tid<o) red[tid]+=red[tid+o]; __syncthreads(); }
  if (tid==0) atomicAdd(acc+b, red[0]);
}

// ---------------- final 0.5(log2pi + z^2) sum ----------------
__global__ __launch_bounds__(256) void final_post_k(
    const float* __restrict__ z, const float* __restrict__ mask, float* __restrict__ acc){
  __shared__ float red[256];
  int b = blockIdx.y; int t = blockIdx.x*256 + threadIdx.x;
  float m = mask[(size_t)b*TTT + t];
  float z0 = z[((size_t)b*2+0)*TTT + t];
  float z1 = z[((size_t)b*2+1)*TTT + t];
  float contrib = 0.5f*(LOG2PI_F + z0*z0)*m + 0.5f*(LOG2PI_F + z1*z1)*m;
  int tid = threadIdx.x;
  red[tid] = contrib;
  __syncthreads();
  for (int o=128;o>0;o>>=1){ if (tid<o) red[tid]+=red[tid+o]; __syncthreads(); }
  if (tid==0) atomicAdd(acc+b, red[0]);
}

__global__ void write_out_k(const float* __restrict__ acc, float* __restrict__ out, int n){
  int i = threadIdx.x;
  if (i < n) out[i] = acc[i];
}

extern "C" void kernel_launch(void* const* d_in, const int* in_sizes, int n_in,
                              void* d_out, int out_size, void* d_ws, size_t ws_size,
                              hipStream_t stream){
  (void)n_in; (void)out_size; (void)ws_size;
  const float* x         = (const float*)d_in[0];
  const float* mask      = (const float*)d_in[1];
  const float* w_in      = (const float*)d_in[2];
  const float* e_q       = (const float*)d_in[3];
  const float* pre_w     = (const float*)d_in[4];
  const float* pre_b     = (const float*)d_in[5];
  const float* proj_w    = (const float*)d_in[6];
  const float* proj_b    = (const float*)d_in[7];
  const float* dds_dep_w = (const float*)d_in[8];
  const float* dds_dep_b = (const float*)d_in[9];
  const float* dds_pw_w  = (const float*)d_in[10];
  const float* dds_pw_b  = (const float*)d_in[11];
  const float* dds_ln_g  = (const float*)d_in[12];
  const float* dds_ln_b  = (const float*)d_in[13];
  const float* post_pre_w  = (const float*)d_in[14];
  const float* post_pre_b  = (const float*)d_in[15];
  const float* post_proj_w = (const float*)d_in[16];
  const float* post_proj_b = (const float*)d_in[17];
  const float* pdds_dep_w  = (const float*)d_in[18];
  const float* pdds_dep_b  = (const float*)d_in[19];
  const float* pdds_pw_w   = (const float*)d_in[20];
  const float* pdds_pw_b   = (const float*)d_in[21];
  const float* pdds_ln_g   = (const float*)d_in[22];
  const float* pdds_ln_b   = (const float*)d_in[23];
  const float* aff_m    = (const float*)d_in[24];
  const float* aff_logs = (const float*)d_in[25];
  const float* f_pre_w  = (const float*)d_in[26];
  const float* f_pre_b  = (const float*)d_in[27];
  const float* f_dep_w  = (const float*)d_in[28];
  const float* f_dep_b  = (const float*)d_in[29];
  const float* f_pw_w   = (const float*)d_in[30];
  const float* f_pw_b   = (const float*)d_in[31];
  const float* f_ln_g   = (const float*)d_in[32];
  const float* f_ln_b   = (const float*)d_in[33];
  const float* f_proj_w = (const float*)d_in[34];
  const float* f_proj_b = (const float*)d_in[35];
  const float* paff_m    = (const float*)d_in[36];
  const float* paff_logs = (const float*)d_in[37];
  const float* p_pre_w  = (const float*)d_in[38];
  const float* p_pre_b  = (const float*)d_in[39];
  const float* p_dep_w  = (const float*)d_in[40];
  const float* p_dep_b  = (const float*)d_in[41];
  const float* p_pw_w   = (const float*)d_in[42];
  const float* p_pw_b   = (const float*)d_in[43];
  const float* p_ln_g   = (const float*)d_in[44];
  const float* p_ln_b   = (const float*)d_in[45];
  const float* p_proj_w = (const float*)d_in[46];
  const float* p_proj_b = (const float*)d_in[47];

  int Bn = in_sizes[0] / (CC*TTT);
  size_t big2 = (size_t)Bn*CC*TTT;   // ushort elements per bf16 buffer
  unsigned short* xT = (unsigned short*)d_ws;
  unsigned short* A  = xT + big2;
  unsigned short* Bb = A  + big2;
  unsigned short* H  = Bb + big2;
  unsigned short* GP = H  + big2;
  unsigned short* Wb = GP + big2;
  size_t wtot = 33*(size_t)WSLOT + 8*(size_t)PSW;
  float* zbuf = (float*)(Wb + ((wtot + 7) & ~(size_t)7));
  float* acc  = zbuf + (size_t)Bn*2*TTT;

  hipMemsetAsync(acc, 0, Bn*sizeof(float), stream);
  convert_w_k<<<(int)((wtot + 255)/256), 256, 0, stream>>>(
      pre_w, proj_w, post_proj_w, dds_pw_w, pdds_pw_w, p_pw_w, f_pw_w,
      p_proj_w, f_proj_w, Wb);

  dim3 g32(TTT/32, Bn), g256(TTT/256, Bn);
  dim3 b256(256);

  unsigned short* W_pre      = Wb + 0*(size_t)WSLOT;
  unsigned short* W_proj     = Wb + 1*(size_t)WSLOT;
  unsigned short* W_postproj = Wb + 2*(size_t)WSLOT;
  unsigned short* W_dds      = Wb + 3*(size_t)WSLOT;
  unsigned short* W_pdds     = Wb + 6*(size_t)WSLOT;
  unsigned short* W_ppw      = Wb + 9*(size_t)WSLOT;
  unsigned short* W_fpw      = Wb + 21*(size_t)WSLOT;
  unsigned short* W_pproj    = Wb + 33*(size_t)WSLOT;
  unsigned short* W_fproj    = W_pproj + 4*(size_t)PSW;

  transpose_x_k<<<g32, b256, 0, stream>>>(x, xT);

  // ---- h path ----
  conv_cc_k<<<g32, b256, 0, stream>>>(xT, W_pre, pre_b, mask, nullptr, A, 0);
  mega_dds_k<<<g32, b256, 0, stream>>>(A, nullptr, 0, nullptr, Bb, mask,
      dds_dep_w, dds_dep_b, dds_ln_g, dds_ln_b, dds_pw_b, nullptr, nullptr,
      W_dds, 0, 0, nullptr, nullptr, nullptr, 0, acc);
  conv_cc_k<<<g32, b256, 0, stream>>>(Bb, W_proj, proj_b, mask, nullptr, H, 1);

  // ---- hw path ----
  mega_dds_k<<<g32, b256, 0, stream>>>(nullptr, w_in, TTT, nullptr, A, mask,
      pdds_dep_w, pdds_dep_b, pdds_ln_g, pdds_ln_b, pdds_pw_b, post_pre_w, post_pre_b,
      W_pdds, 1, 0, nullptr, nullptr, nullptr, 0, acc);
  conv_cc_k<<<g32, b256, 0, stream>>>(A, W_postproj, post_proj_b, mask, H, GP, 2);

  // ---- init z ----
  init_z_k<<<g256, b256, 0, stream>>>(e_q, mask, paff_m, paff_logs, zbuf, acc);

  // ---- 4 posterior flows (g = GP) ----
  for (int f=0; f<4; f++){
    int s = f & 1;
    mega_dds_k<<<g32, b256, 0, stream>>>(nullptr, zbuf + (size_t)s*TTT, 2*TTT, GP, nullptr, mask,
        p_dep_w + (size_t)f*3*CC*3, p_dep_b + (size_t)f*3*CC,
        p_ln_g + (size_t)f*3*2*CC, p_ln_b + (size_t)f*3*2*CC,
        p_pw_b + (size_t)f*3*CC,
        p_pre_w + (size_t)f*CC, p_pre_b + (size_t)f*CC,
        W_ppw + (size_t)f*3*WSLOT, 1, 1,
        W_pproj + (size_t)f*PSW, p_proj_b + (size_t)f*PP, zbuf, s, acc);
  }

  // ---- transition ----
  final_pre_k<<<g256, b256, 0, stream>>>(zbuf, w_in, mask, aff_m, aff_logs, acc);

  // ---- 4 flows (g = H) ----
  for (int f=0; f<4; f++){
    int s = f & 1;
    mega_dds_k<<<g32, b256, 0, stream>>>(nullptr, zbuf + (size_t)s*TTT, 2*TTT, H, nullptr, mask,
        f_dep_w + (size_t)f*3*CC*3, f_dep_b + (size_t)f*3*CC,
        f_ln_g + (size_t)f*3*2*CC, f_ln_b + (size_t)f*3*2*CC,
        f_pw_b + (size_t)f*3*CC,
        f_pre_w + (size_t)f*CC, f_pre_b + (size_t)f*CC,
        W_fpw + (size_t)f*3*WSLOT, 1, 1,
        W_fproj + (size_t)f*PSW, f_proj_b + (size_t)f*PP, zbuf, s, acc);
  }

  final_post_k<<<g256, b256, 0, stream>>>(zbuf, mask, acc);
  write_out_k<<<1, 64, 0, stream>>>(acc, (float*)d_out, Bn);
}

// Round 6
// 995.010 us; speedup vs baseline: 1.2802x; 1.1919x over previous
//
#include <hip/hip_runtime.h>
#include <math.h>

#define CC 192
#define TTT 768
#define PP 29
#define LOG2PI_F 1.8378770664093453f
#define WSLOT 36864   // swizzled 192x192 slot (elements)
#define PSW 6144      // swizzled 32x192 proj slot (elements)
#define XS 200        // ushort stride for [t][c] bf16 LDS tiles

typedef __attribute__((ext_vector_type(8))) short short8;
typedef __attribute__((ext_vector_type(4))) float floatx4;
typedef __attribute__((ext_vector_type(2))) float float2v;
union Frag { int4 i; short8 s; };

__device__ __forceinline__ float2v fma2(float2v a, float2v b, float2v c){
  return __builtin_elementwise_fma(a, b, c);
}
__device__ __forceinline__ float geluf(float x){
  float u = 1.5957691216057308f * (x + 0.044715f*x*x*x);
  return x * __builtin_amdgcn_rcpf(1.f + __expf(-u));
}
__device__ __forceinline__ float softplus_f(float x){
  return (x > 20.f) ? x : log1pf(__expf(x));
}
__device__ __forceinline__ float logsig_f(float x){
  return -softplus_f(-x);
}
__device__ __forceinline__ unsigned short f2bf(float f){
  unsigned int u = __builtin_bit_cast(unsigned int, f);
  u += 0x7fffu + ((u >> 16) & 1u);
  return (unsigned short)(u >> 16);
}
__device__ __forceinline__ unsigned int packbf2(float a0, float a1){
  return (unsigned int)f2bf(a0) | ((unsigned int)f2bf(a1) << 16);
}
__device__ __forceinline__ void unbf2(unsigned int u, float& lo, float& hi){
  lo = __builtin_bit_cast(float, u << 16);
  hi = __builtin_bit_cast(float, u & 0xffff0000u);
}
__device__ __forceinline__ float2v unbf2v(unsigned int u){
  float2v r;
  r.x = __builtin_bit_cast(float, u << 16);
  r.y = __builtin_bit_cast(float, u & 0xffff0000u);
  return r;
}
__device__ __forceinline__ void unp8(int4 v, float* o){
  unsigned int* p = (unsigned int*)&v;
  unbf2(p[0], o[0], o[1]); unbf2(p[1], o[2], o[3]);
  unbf2(p[2], o[4], o[5]); unbf2(p[3], o[6], o[7]);
}
__device__ __forceinline__ void f4arr(float4 v, float* o){ o[0]=v.x;o[1]=v.y;o[2]=v.z;o[3]=v.w; }

// ---------------- weight f32 -> bf16 swizzled fragment order ----------------
__global__ __launch_bounds__(256) void convert_w_k(
    const float* __restrict__ p0, const float* __restrict__ p1,
    const float* __restrict__ p2, const float* __restrict__ p3,
    const float* __restrict__ p4, const float* __restrict__ p5,
    const float* __restrict__ p6, const float* __restrict__ p7,
    const float* __restrict__ p8, unsigned short* __restrict__ Wb){
  int i = blockIdx.x*256 + threadIdx.x;
  const int totalA = 33*WSLOT;
  const int total = totalA + 8*PSW;
  if (i >= total) return;
  if (i < totalA){
    int slot = i / WSLOT, j = i % WSLOT;
    int e = j & 7, lane = (j>>3) & 63, kt = j >> 9;
    int k = kt % 6, tile = kt / 6;
    int co = tile*16 + (lane & 15);
    int kk = k*32 + (lane>>4)*8 + e;
    int r = co*CC + kk;
    const float* src;
    if      (slot == 0) src = p0 + r;
    else if (slot == 1) src = p1 + r;
    else if (slot == 2) src = p2 + r;
    else if (slot < 6)  src = p3 + (size_t)(slot-3)*WSLOT + r;
    else if (slot < 9)  src = p4 + (size_t)(slot-6)*WSLOT + r;
    else if (slot < 21) src = p5 + (size_t)(slot-9)*WSLOT + r;
    else                src = p6 + (size_t)(slot-21)*WSLOT + r;
    Wb[i] = f2bf(*src);
  } else {
    int r2 = i - totalA;
    int ps = r2 / PSW, j = r2 % PSW;
    int e = j & 7, lane = (j>>3) & 63, kt = j >> 9;
    int k = kt % 6, tile = kt / 6;
    int co = tile*16 + (lane & 15); if (co > PP-1) co = PP-1;
    int kk = k*32 + (lane>>4)*8 + e;
    const float* base = (ps < 4) ? (p7 + (size_t)ps*PP*CC) : (p8 + (size_t)(ps-4)*PP*CC);
    Wb[i] = f2bf(base[co*CC + kk]);
  }
}

// ---------------- x f32 [B][C][T] -> bf16 [B][T][C] ----------------
__global__ __launch_bounds__(256) void transpose_x_k(
    const float* __restrict__ x, unsigned short* __restrict__ xT){
  __shared__ unsigned short tile[32*XS];
  int b = blockIdx.y, t0 = blockIdx.x*32, tid = threadIdx.x;
  int tl4 = (tid & 7)*4, cr = tid >> 3;
  #pragma unroll
  for (int rnd=0; rnd<6; rnd++){
    int c = rnd*32 + cr;
    float4 v4 = *(const float4*)(x + ((size_t)b*CC + c)*TTT + t0 + tl4);
    tile[(tl4+0)*XS + c] = f2bf(v4.x);
    tile[(tl4+1)*XS + c] = f2bf(v4.y);
    tile[(tl4+2)*XS + c] = f2bf(v4.z);
    tile[(tl4+3)*XS + c] = f2bf(v4.w);
  }
  __syncthreads();
  #pragma unroll
  for (int k=0;k<3;k++){
    int task = k*256 + tid;
    int row = task/24, cn = task%24;
    *(int4*)(xT + ((size_t)b*TTT + t0 + row)*CC + cn*8) = *(const int4*)&tile[row*XS + cn*8];
  }
}

// ---------------- conv 192x192 bf16 MFMA, t-major bf16 in/out ----------------
__global__ __launch_bounds__(256) void conv_cc_k(
    const unsigned short* __restrict__ in, const unsigned short* __restrict__ Wsw,
    const float* __restrict__ bias, const float* __restrict__ mask,
    const unsigned short* __restrict__ addsrc, unsigned short* __restrict__ outb, int mode){
  __shared__ unsigned short bufX[32*XS];
  __shared__ unsigned short bufY[32*XS];
  __shared__ float marr[32];
  int b = blockIdx.y, t0 = blockIdx.x*32, tid = threadIdx.x;
  #pragma unroll
  for (int k=0;k<3;k++){
    int task = k*256 + tid;
    int row = task/24, cn = task%24;
    const unsigned short* src = in + ((size_t)b*TTT + t0 + row)*CC + cn*8;
    *(int4*)&bufX[row*XS + cn*8] = *(const int4*)src;
    if (mode == 2){
      const unsigned short* s2 = addsrc + ((size_t)b*TTT + t0 + row)*CC + cn*8;
      *(int4*)&bufY[row*XS + cn*8] = *(const int4*)s2;
    }
  }
  if (tid >= 128 && tid < 160) marr[tid-128] = mask[(size_t)b*TTT + t0 + (tid-128)];
  __syncthreads();
  int w = tid >> 6, lane = tid & 63;
  int n16 = lane & 15, quad = lane >> 4;
  Frag af[3][6];
  #pragma unroll
  for (int ct=0; ct<3; ct++){
    int tile = w*3 + ct;
    #pragma unroll
    for (int k=0;k<6;k++)
      af[ct][k].i = *(const int4*)(Wsw + ((size_t)(tile*6 + k)*64 + lane)*8);
  }
  floatx4 acc[3][2];
  #pragma unroll
  for (int ct=0;ct<3;ct++)
    #pragma unroll
    for (int tt=0;tt<2;tt++)
      acc[ct][tt] = (floatx4){0.f,0.f,0.f,0.f};
  #pragma unroll
  for (int k=0;k<6;k++){
    Frag bf[2];
    #pragma unroll
    for (int tt=0;tt<2;tt++)
      bf[tt].i = *(const int4*)&bufX[(tt*16+n16)*XS + k*32 + quad*8];
    #pragma unroll
    for (int ct=0;ct<3;ct++)
      #pragma unroll
      for (int tt=0;tt<2;tt++)
        acc[ct][tt] = __builtin_amdgcn_mfma_f32_16x16x32_bf16(af[ct][k].s, bf[tt].s, acc[ct][tt], 0,0,0);
  }
  __syncthreads();
  #pragma unroll
  for (int ct=0;ct<3;ct++){
    int cobase = w*48 + ct*16 + quad*4;
    float4 b4 = *(const float4*)(bias + cobase);
    float ba[4] = {b4.x, b4.y, b4.z, b4.w};
    #pragma unroll
    for (int tt=0;tt<2;tt++){
      int t = tt*16 + n16;
      float mv = (mode >= 1) ? marr[t] : 1.f;
      float av[4] = {0.f,0.f,0.f,0.f};
      if (mode == 2){
        uint2 uy = *(uint2*)&bufY[t*XS + cobase];
        unbf2(uy.x, av[0], av[1]); unbf2(uy.y, av[2], av[3]);
      }
      float hh[4];
      #pragma unroll
      for (int r=0;r<4;r++){
        float v = acc[ct][tt][r] + ba[r];
        if (mode >= 1) v *= mv;
        if (mode == 2) v += av[r];
        hh[r] = v;
      }
      uint2 wv; wv.x = packbf2(hh[0], hh[1]); wv.y = packbf2(hh[2], hh[3]);
      *(uint2*)&bufX[t*XS + cobase] = wv;
    }
  }
  __syncthreads();
  #pragma unroll
  for (int k=0;k<3;k++){
    int task = k*256 + tid;
    int row = task/24, cn = task%24;
    *(int4*)(outb + ((size_t)b*TTT + t0 + row)*CC + cn*8) = *(const int4*)&bufX[row*XS + cn*8];
  }
}

// ---------------- mega DDS: 3 fused layers (+ optional proj+spline) ----------------
__global__ __launch_bounds__(256,3) void mega_dds_k(
    const unsigned short* __restrict__ in,
    const float* __restrict__ zsrc, int zstride,
    const unsigned short* __restrict__ g,
    unsigned short* __restrict__ outb,
    const float* __restrict__ mask,
    const float* __restrict__ dwB, const float* __restrict__ dbB,
    const float* __restrict__ lngB, const float* __restrict__ lnbB,
    const float* __restrict__ pwbB,
    const float* __restrict__ pw1, const float* __restrict__ pb1,
    const unsigned short* __restrict__ Wsw,
    int srcmode, int outmode,
    const unsigned short* __restrict__ projW, const float* __restrict__ projB,
    float* __restrict__ z, int zs, float* __restrict__ acco){
  __shared__ unsigned short ping[64*XS];   // residual stream (bf16 [row][c])
  __shared__ unsigned short pong[64*XS];   // gelu'd conv input; later aliased as pro
  __shared__ float2v redSQ[64*4];          // per-row (sum, sumsq) partials, 4 waves
  __shared__ float mrow[64];
  __shared__ float mst[64], rst[64];       // mst reused as spline sred
  float* pro = (float*)pong;

  int b = blockIdx.y, t0 = blockIdx.x*32, tid = threadIdx.x;
  int ws0 = t0 - 16;
  int w = tid >> 6, lane = tid & 63;
  int n16 = lane & 15, quad = lane >> 4;
  int wu = __builtin_amdgcn_readfirstlane(w);
  const int dils[3] = {1,3,9};

  // ---- S0: mask window ----
  if (tid < 64){
    int gt = ws0 + tid;
    bool inr = (gt >= 0) && (gt < TTT);
    int gc = gt < 0 ? 0 : (gt > TTT-1 ? TTT-1 : gt);
    mrow[tid] = inr ? mask[(size_t)b*TTT + gc] : 0.f;
  }
  // ---- S1: stage x window into ping ----
  if (srcmode == 0){
    #pragma unroll
    for (int k=0;k<6;k++){
      int task = k*256 + tid;
      if (task < 1536){
        int row = task/24, cn = task%24;
        int gt = ws0 + row; gt = gt < 0 ? 0 : (gt > TTT-1 ? TTT-1 : gt);
        *(int4*)&ping[row*XS + cn*8] = *(const int4*)(in + ((size_t)b*TTT + gt)*CC + cn*8);
      }
    }
  } else {
    #pragma unroll
    for (int k=0;k<6;k++){
      int task = k*256 + tid;
      if (task < 1536){
        int row = task/24, cn = task%24;
        int gt = ws0 + row;
        bool inr = (gt >= 0) && (gt < TTT);
        int gc = gt < 0 ? 0 : (gt > TTT-1 ? TTT-1 : gt);
        float zv = inr ? zsrc[(size_t)b*zstride + gc] : 0.f;
        int c0 = cn*8;
        float hv[8];
        if (g){
          int4 gg = *(const int4*)(g + ((size_t)b*TTT + gc)*CC + c0);
          unp8(gg, hv);
        } else {
          #pragma unroll
          for (int e=0;e<8;e++) hv[e] = 0.f;
        }
        float4 pwa = *(const float4*)(pw1 + c0);
        float4 pwb = *(const float4*)(pw1 + c0 + 4);
        float4 pba = *(const float4*)(pb1 + c0);
        float4 pbb = *(const float4*)(pb1 + c0 + 4);
        float pwv[8], pbv[8];
        f4arr(pwa, pwv); f4arr(pwb, pwv+4);
        f4arr(pba, pbv); f4arr(pbb, pbv+4);
        unsigned int ww[4];
        #pragma unroll
        for (int e2=0;e2<4;e2++){
          float a0 = hv[2*e2]   + fmaf(pwv[2*e2],   zv, pbv[2*e2]);
          float a1 = hv[2*e2+1] + fmaf(pwv[2*e2+1], zv, pbv[2*e2+1]);
          ww[e2] = packbf2(a0, a1);
        }
        *(int4*)&ping[row*XS + c0] = *(int4*)ww;
      }
    }
  }
  __syncthreads();

  // ---- 3 fused layers ----
  #pragma unroll
  for (int l=0; l<3; l++){
    const int dil = dils[l];
    const int tlo = (l==2) ? 1 : 0;
    const int thi = (l==2) ? 2 : 3;
    float2v vv[24];
    // P1: depthwise (row = lane, 48 ch per wave-group)
    {
      int i = lane;
      int c0u = wu*48;
      const float* dwl = dwB + l*CC*3;
      const float* dbl = dbB + l*CC;
      int iL = i - dil; int iLc = iL < 0 ? 0 : iL;
      int iR = i + dil; int iRc = iR > 63 ? 63 : iR;
      float ml = (iL >= 0) ? mrow[iLc] : 0.f;
      float mc = mrow[i];
      float mr = (iR <= 63) ? mrow[iRc] : 0.f;
      float2v ml2 = {ml,ml}, mc2 = {mc,mc}, mr2 = {mr,mr};
      float2v s2 = {0.f,0.f}, q2 = {0.f,0.f};
      #pragma unroll
      for (int j=0;j<6;j++){
        int c = c0u + j*8;
        int4 L4 = *(const int4*)&ping[iLc*XS + c];
        int4 C4 = *(const int4*)&ping[i  *XS + c];
        int4 R4 = *(const int4*)&ping[iRc*XS + c];
        unsigned int* Lp = (unsigned int*)&L4;
        unsigned int* Cp = (unsigned int*)&C4;
        unsigned int* Rp = (unsigned int*)&R4;
        #pragma unroll
        for (int p=0;p<4;p++){
          int cc = c + 2*p;
          float2v w0 = {dwl[cc*3],   dwl[cc*3+3]};
          float2v w1 = {dwl[cc*3+1], dwl[cc*3+4]};
          float2v w2 = {dwl[cc*3+2], dwl[cc*3+5]};
          float2v bb = {dbl[cc], dbl[cc+1]};
          float2v val = fma2(w0, unbf2v(Lp[p])*ml2,
                        fma2(w1, unbf2v(Cp[p])*mc2,
                        fma2(w2, unbf2v(Rp[p])*mr2, bb)));
          vv[j*4+p] = val;
          s2 += val; q2 = fma2(val, val, q2);
        }
      }
      redSQ[i*4 + w] = (float2v){s2.x+s2.y, q2.x+q2.y};
    }
    __syncthreads();
    if (tid < 64){
      float2v a = redSQ[tid*4+0] + redSQ[tid*4+1] + redSQ[tid*4+2] + redSQ[tid*4+3];
      float m = a.x*(1.f/CC);
      mst[tid] = m; rst[tid] = rsqrtf(a.y*(1.f/CC) - m*m + 1e-5f);
    }
    __syncthreads();
    // P3: LN + gelu -> pong
    {
      int i = lane;
      int c0u = wu*48;
      const float* g0p = lngB + (l*2)*CC;
      const float* b0p = lnbB + (l*2)*CC;
      float mm = mst[i], rr = rst[i];
      float2v mm2 = {mm,mm}, rr2 = {rr,rr};
      #pragma unroll
      for (int j=0;j<6;j++){
        int c = c0u + j*8;
        unsigned int ww[4];
        #pragma unroll
        for (int p=0;p<4;p++){
          int cc = c + 2*p;
          float2v gg = {g0p[cc], g0p[cc+1]};
          float2v bb = {b0p[cc], b0p[cc+1]};
          float2v t = (vv[j*4+p] - mm2)*rr2;
          float2v a = fma2(t, gg, bb);
          ww[p] = packbf2(geluf(a.x), geluf(a.y));
        }
        *(int4*)&pong[i*XS + c] = *(int4*)ww;
      }
    }
    __syncthreads();
    // P4: conv via MFMA
    floatx4 acc4[3][4];
    {
      Frag af[3][6];
      const unsigned short* WL = Wsw + (size_t)l*WSLOT;
      #pragma unroll
      for (int ct=0; ct<3; ct++){
        int tile = w*3 + ct;
        #pragma unroll
        for (int k=0;k<6;k++)
          af[ct][k].i = *(const int4*)(WL + ((size_t)(tile*6 + k)*64 + lane)*8);
      }
      #pragma unroll
      for (int ct=0;ct<3;ct++)
        #pragma unroll
        for (int tt=0;tt<4;tt++)
          acc4[ct][tt] = (floatx4){0.f,0.f,0.f,0.f};
      #pragma unroll
      for (int k=0;k<6;k++){
        Frag bf[4];
        #pragma unroll
        for (int tt=0;tt<4;tt++){
          if (tt < tlo || tt > thi) continue;
          bf[tt].i = *(const int4*)&pong[(tt*16+n16)*XS + k*32 + quad*8];
        }
        #pragma unroll
        for (int ct=0;ct<3;ct++)
          #pragma unroll
          for (int tt=0;tt<4;tt++){
            if (tt < tlo || tt > thi) continue;
            acc4[ct][tt] = __builtin_amdgcn_mfma_f32_16x16x32_bf16(af[ct][k].s, bf[tt].s, acc4[ct][tt], 0,0,0);
          }
      }
    }
    // bias + per-row stats (in-wave quad reduction)
    {
      const float* pbp = pwbB + l*CC;
      #pragma unroll
      for (int ct=0;ct<3;ct++){
        int cobase = w*48 + ct*16 + quad*4;
        float4 pbv = *(const float4*)(pbp + cobase);
        float pba[4]; f4arr(pbv, pba);
        #pragma unroll
        for (int tt=0;tt<4;tt++){
          if (tt < tlo || tt > thi) continue;
          #pragma unroll
          for (int r=0;r<4;r++)
            acc4[ct][tt][r] += pba[r];
        }
      }
      #pragma unroll
      for (int tt=0;tt<4;tt++){
        if (tt < tlo || tt > thi) continue;
        float ps=0.f, pq=0.f;
        #pragma unroll
        for (int ct=0;ct<3;ct++)
          #pragma unroll
          for (int r=0;r<4;r++){ float x = acc4[ct][tt][r]; ps += x; pq = fmaf(x,x,pq); }
        ps += __shfl_xor(ps, 16); ps += __shfl_xor(ps, 32);
        pq += __shfl_xor(pq, 16); pq += __shfl_xor(pq, 32);
        if (quad == 0) redSQ[(tt*16+n16)*4 + w] = (float2v){ps, pq};
      }
    }
    __syncthreads();
    if (tid < 64){
      float2v a = redSQ[tid*4+0] + redSQ[tid*4+1] + redSQ[tid*4+2] + redSQ[tid*4+3];
      float m = a.x*(1.f/CC);
      mst[tid] = m; rst[tid] = rsqrtf(a.y*(1.f/CC) - m*m + 1e-5f);
    }
    __syncthreads();
    // P6: LN + gelu + residual (in-place into ping)
    {
      const float* g1p = lngB + (l*2+1)*CC;
      const float* b1p = lnbB + (l*2+1)*CC;
      #pragma unroll
      for (int ct=0;ct<3;ct++){
        int cobase = w*48 + ct*16 + quad*4;
        float4 g1v = *(const float4*)(g1p + cobase);
        float4 b1v = *(const float4*)(b1p + cobase);
        #pragma unroll
        for (int tt=0;tt<4;tt++){
          if (tt < tlo || tt > thi) continue;
          int row = tt*16 + n16;
          float mm = mst[row], rr = rst[row];
          float2v mm2 = {mm,mm}, rr2 = {rr,rr};
          uint2 ux = *(uint2*)&ping[row*XS + cobase];
          float2v x01 = unbf2v(ux.x), x23 = unbf2v(ux.y);
          float2v v01 = {acc4[ct][tt][0], acc4[ct][tt][1]};
          float2v v23 = {acc4[ct][tt][2], acc4[ct][tt][3]};
          float2v a01 = fma2((v01-mm2)*rr2, (float2v){g1v.x,g1v.y}, (float2v){b1v.x,b1v.y});
          float2v a23 = fma2((v23-mm2)*rr2, (float2v){g1v.z,g1v.w}, (float2v){b1v.z,b1v.w});
          float h0 = x01.x + geluf(a01.x);
          float h1 = x01.y + geluf(a01.y);
          float h2 = x23.x + geluf(a23.x);
          float h3 = x23.y + geluf(a23.y);
          uint2 wv; wv.x = packbf2(h0, h1); wv.y = packbf2(h2, h3);
          *(uint2*)&ping[row*XS + cobase] = wv;
        }
      }
    }
    __syncthreads();
  }

  if (outmode == 0){
    #pragma unroll
    for (int k=0;k<3;k++){
      int task = k*256 + tid;
      int row = task/24, cn = task%24;
      *(int4*)(outb + ((size_t)b*TTT + t0 + row)*CC + cn*8) = *(const int4*)&ping[(16+row)*XS + cn*8];
    }
    return;
  }

  // ---- proj (29x192) on center 32 rows: waves 0,1 ----
  if (w < 2){
    Frag pf[2][6];
    #pragma unroll
    for (int ct2=0; ct2<2; ct2++)
      #pragma unroll
      for (int k=0;k<6;k++)
        pf[ct2][k].i = *(const int4*)(projW + ((size_t)(ct2*6 + k)*64 + lane)*8);
    floatx4 acc2[2];
    acc2[0] = (floatx4){0.f,0.f,0.f,0.f};
    acc2[1] = (floatx4){0.f,0.f,0.f,0.f};
    #pragma unroll
    for (int k=0;k<6;k++){
      Frag bf;
      bf.i = *(const int4*)&ping[(16 + w*16 + n16)*XS + k*32 + quad*8];
      #pragma unroll
      for (int ct2=0;ct2<2;ct2++)
        acc2[ct2] = __builtin_amdgcn_mfma_f32_16x16x32_bf16(pf[ct2][k].s, bf.s, acc2[ct2], 0,0,0);
    }
    #pragma unroll
    for (int ct2=0;ct2<2;ct2++){
      int cobase = ct2*16 + quad*4;
      int rt = w*16 + n16;
      float mv = mrow[16+rt];
      #pragma unroll
      for (int r=0;r<4;r++){
        int co = cobase + r;
        if (co < PP) pro[rt*30 + co] = (acc2[ct2][r] + projB[co]) * mv;
      }
    }
  }
  __syncthreads();
  // ---- RQS spline on 32 lanes ----
  if (tid < 32){
    const float scv = 0.07216878364870323f;   // 1/sqrt(192)
    int tg = t0 + tid;
    float m = mrow[16+tid];
    float* z0p = z + ((size_t)b*2 + zs)*TTT + tg;
    float* z1p = z + ((size_t)b*2 + (1-zs))*TTT + tg;
    float xs = *z1p;
    float uw[10], uh[10], ud[9];
    #pragma unroll
    for (int k=0;k<10;k++) uw[k]=pro[tid*30+k]*scv;
    #pragma unroll
    for (int k=0;k<10;k++) uh[k]=pro[tid*30+10+k]*scv;
    #pragma unroll
    for (int k=0;k<9;k++)  ud[k]=pro[tid*30+20+k];
    bool inside = (xs >= -5.f) && (xs <= 5.f);
    float xc = fminf(fmaxf(xs,-5.f),5.f);
    float mx=uw[0];
    #pragma unroll
    for (int k=1;k<10;k++) mx=fmaxf(mx,uw[k]);
    float sw=0.f; float wd[10];
    #pragma unroll
    for (int k=0;k<10;k++){ wd[k]=__expf(uw[k]-mx); sw+=wd[k]; }
    float invw = 1.f/sw;
    #pragma unroll
    for (int k=0;k<10;k++) wd[k]=fmaf(0.99f*invw, wd[k], 1e-3f);
    float mh=uh[0];
    #pragma unroll
    for (int k=1;k<10;k++) mh=fmaxf(mh,uh[k]);
    float sh=0.f; float ht[10];
    #pragma unroll
    for (int k=0;k<10;k++){ ht[k]=__expf(uh[k]-mh); sh+=ht[k]; }
    float invh = 1.f/sh;
    #pragma unroll
    for (int k=0;k<10;k++) ht[k]=fmaf(0.99f*invh, ht[k], 1e-3f);
    float cw=-5.f, icw=-5.f, iw=1.f; int idx=0;
    #pragma unroll
    for (int i2=0;i2<10;i2++){
      float nw = (i2==9) ? 5.f : fmaf(10.f, wd[i2], cw);
      if (cw <= xc){ idx=i2; icw=cw; iw=nw-cw; }
      cw=nw;
    }
    float ch=-5.f, ich=-5.f, ih=1.f;
    #pragma unroll
    for (int i2=0;i2<10;i2++){
      float nh = (i2==9) ? 5.f : fmaf(10.f, ht[i2], ch);
      if (i2==idx){ ich=ch; ih=nh-ch; }
      ch=nh;
    }
    const float UDC = logf(expm1f(0.999f));
    float d0=1.f, d1=1.f;
    #pragma unroll
    for (int k=0;k<11;k++){
      float uu = (k==0 || k==10) ? UDC : ud[k-1];
      float dk = 1e-3f + softplus_f(uu);
      if (k==idx)   d0=dk;
      if (k==idx+1) d1=dk;
    }
    float idel = ih/iw;
    float th = (xc-icw)/iw;
    float t1m = th*(1.f-th);
    float den = idel + (d0+d1-2.f*idel)*t1m;
    float outv = ich + ih*(idel*th*th + d0*t1m)/den;
    float omt = 1.f-th;
    float dnum = idel*idel*(d1*th*th + 2.f*idel*t1m + d0*omt*omt);
    float lad = logf(dnum) - 2.f*logf(den);
    float y = inside ? outv : xs;
    lad = inside ? lad : 0.f;
    *z1p = y*m;
    *z0p = (*z0p)*m;
    mst[tid] = lad*m;
  }
  __syncthreads();
  if (tid == 0){
    float ssum = 0.f;
    #pragma unroll
    for (int i2=0;i2<32;i2++) ssum += mst[i2];
    atomicAdd(acco + b, -ssum);
  }
}

// ---------------- z init ----------------
__global__ __launch_bounds__(256) void init_z_k(
    const float* __restrict__ e_q, const float* __restrict__ mask,
    const float* __restrict__ pm, const float* __restrict__ pl,
    float* __restrict__ z, float* __restrict__ acc){
  __shared__ float red[256];
  int b = blockIdx.y; int t = blockIdx.x*256 + threadIdx.x;
  float m = mask[(size_t)b*TTT + t];
  float pl0=pl[0], pl1=pl[1];
  float e0 = e_q[((size_t)b*2+0)*TTT + t]*m;
  float e1 = e_q[((size_t)b*2+1)*TTT + t]*m;
  z[((size_t)b*2+0)*TTT + t] = fmaf(__expf(pl0), e0, pm[0])*m;
  z[((size_t)b*2+1)*TTT + t] = fmaf(__expf(pl1), e1, pm[1])*m;
  float contrib = -0.5f*(LOG2PI_F + e0*e0)*m - 0.5f*(LOG2PI_F + e1*e1)*m - (pl0+pl1)*m;
  int tid = threadIdx.x;
  red[tid] = contrib;
  __syncthreads();
  for (int o=128;o>0;o>>=1){ if (tid<o) red[tid]+=red[tid+o]; __syncthreads(); }
  if (tid==0) atomicAdd(acc+b, red[0]);
}

// ---------------- between p-flows and f-flows ----------------
__global__ __launch_bounds__(256) void final_pre_k(
    float* __restrict__ z, const float* __restrict__ w_in, const float* __restrict__ mask,
    const float* __restrict__ am, const float* __restrict__ al, float* __restrict__ acc){
  __shared__ float red[256];
  int b = blockIdx.y; int t = blockIdx.x*256 + threadIdx.x;
  float m = mask[(size_t)b*TTT + t];
  float zu  = z[((size_t)b*2+0)*TTT + t];
  float z1v = z[((size_t)b*2+1)*TTT + t];
  float wv  = w_in[(size_t)b*TTT + t];
  float u  = m / (1.f + __expf(-zu));
  float z0 = (wv - u)*m;
  float y0 = logf(fmaxf(z0, 1e-5f))*m;
  float al0=al[0], al1=al[1];
  z[((size_t)b*2+0)*TTT + t] = fmaf(__expf(al0), y0,  am[0])*m;
  z[((size_t)b*2+1)*TTT + t] = fmaf(__expf(al1), z1v, am[1])*m;
  float contrib = -(logsig_f(zu)+logsig_f(-zu))*m + y0 - (al0+al1)*m;
  int tid = threadIdx.x;
  red[tid] = contrib;
  __syncthreads();
  for (int o=128;o>0;o>>=1){ if (tid<o) red[tid]+=red[tid+o]; __syncthreads(); }
  if (tid==0) atomicAdd(acc+b, red[0]);
}

// ---------------- final 0.5(log2pi + z^2) sum ----------------
__global__ __launch_bounds__(256) void final_post_k(
    const float* __restrict__ z, const float* __restrict__ mask, float* __restrict__ acc){
  __shared__ float red[256];
  int b = blockIdx.y; int t = blockIdx.x*256 + threadIdx.x;
  float m = mask[(size_t)b*TTT + t];
  float z0 = z[((size_t)b*2+0)*TTT + t];
  float z1 = z[((size_t)b*2+1)*TTT + t];
  float contrib = 0.5f*(LOG2PI_F + z0*z0)*m + 0.5f*(LOG2PI_F + z1*z1)*m;
  int tid = threadIdx.x;
  red[tid] = contrib;
  __syncthreads();
  for (int o=128;o>0;o>>=1){ if (tid<o) red[tid]+=red[tid+o]; __syncthreads(); }
  if (tid==0) atomicAdd(acc+b, red[0]);
}

__global__ void write_out_k(const float* __restrict__ acc, float* __restrict__ out, int n){
  int i = threadIdx.x;
  if (i < n) out[i] = acc[i];
}

extern "C" void kernel_launch(void* const* d_in, const int* in_sizes, int n_in,
                              void* d_out, int out_size, void* d_ws, size_t ws_size,
                              hipStream_t stream){
  (void)n_in; (void)out_size; (void)ws_size;
  const float* x         = (const float*)d_in[0];
  const float* mask      = (const float*)d_in[1];
  const float* w_in      = (const float*)d_in[2];
  const float* e_q       = (const float*)d_in[3];
  const float* pre_w     = (const float*)d_in[4];
  const float* pre_b     = (const float*)d_in[5];
  const float* proj_w    = (const float*)d_in[6];
  const float* proj_b    = (const float*)d_in[7];
  const float* dds_dep_w = (const float*)d_in[8];
  const float* dds_dep_b = (const float*)d_in[9];
  const float* dds_pw_w  = (const float*)d_in[10];
  const float* dds_pw_b  = (const float*)d_in[11];
  const float* dds_ln_g  = (const float*)d_in[12];
  const float* dds_ln_b  = (const float*)d_in[13];
  const float* post_pre_w  = (const float*)d_in[14];
  const float* post_pre_b  = (const float*)d_in[15];
  const float* post_proj_w = (const float*)d_in[16];
  const float* post_proj_b = (const float*)d_in[17];
  const float* pdds_dep_w  = (const float*)d_in[18];
  const float* pdds_dep_b  = (const float*)d_in[19];
  const float* pdds_pw_w   = (const float*)d_in[20];
  const float* pdds_pw_b   = (const float*)d_in[21];
  const float* pdds_ln_g   = (const float*)d_in[22];
  const float* pdds_ln_b   = (const float*)d_in[23];
  const float* aff_m    = (const float*)d_in[24];
  const float* aff_logs = (const float*)d_in[25];
  const float* f_pre_w  = (const float*)d_in[26];
  const float* f_pre_b  = (const float*)d_in[27];
  const float* f_dep_w  = (const float*)d_in[28];
  const float* f_dep_b  = (const float*)d_in[29];
  const float* f_pw_w   = (const float*)d_in[30];
  const float* f_pw_b   = (const float*)d_in[31];
  const float* f_ln_g   = (const float*)d_in[32];
  const float* f_ln_b   = (const float*)d_in[33];
  const float* f_proj_w = (const float*)d_in[34];
  const float* f_proj_b = (const float*)d_in[35];
  const float* paff_m    = (const float*)d_in[36];
  const float* paff_logs = (const float*)d_in[37];
  const float* p_pre_w  = (const float*)d_in[38];
  const float* p_pre_b  = (const float*)d_in[39];
  const float* p_dep_w  = (const float*)d_in[40];
  const float* p_dep_b  = (const float*)d_in[41];
  const float* p_pw_w   = (const float*)d_in[42];
  const float* p_pw_b   = (const float*)d_in[43];
  const float* p_ln_g   = (const float*)d_in[44];
  const float* p_ln_b   = (const float*)d_in[45];
  const float* p_proj_w = (const float*)d_in[46];
  const float* p_proj_b = (const float*)d_in[47];

  int Bn = in_sizes[0] / (CC*TTT);
  size_t big2 = (size_t)Bn*CC*TTT;
  unsigned short* xT = (unsigned short*)d_ws;
  unsigned short* A  = xT + big2;
  unsigned short* Bb = A  + big2;
  unsigned short* H  = Bb + big2;
  unsigned short* GP = H  + big2;
  unsigned short* Wb = GP + big2;
  size_t wtot = 33*(size_t)WSLOT + 8*(size_t)PSW;
  float* zbuf = (float*)(Wb + ((wtot + 7) & ~(size_t)7));
  float* acc  = zbuf + (size_t)Bn*2*TTT;

  hipMemsetAsync(acc, 0, Bn*sizeof(float), stream);
  convert_w_k<<<(int)((wtot + 255)/256), 256, 0, stream>>>(
      pre_w, proj_w, post_proj_w, dds_pw_w, pdds_pw_w, p_pw_w, f_pw_w,
      p_proj_w, f_proj_w, Wb);

  dim3 g32(TTT/32, Bn), g256(TTT/256, Bn);
  dim3 b256(256);

  unsigned short* W_pre      = Wb + 0*(size_t)WSLOT;
  unsigned short* W_proj     = Wb + 1*(size_t)WSLOT;
  unsigned short* W_postproj = Wb + 2*(size_t)WSLOT;
  unsigned short* W_dds      = Wb + 3*(size_t)WSLOT;
  unsigned short* W_pdds     = Wb + 6*(size_t)WSLOT;
  unsigned short* W_ppw      = Wb + 9*(size_t)WSLOT;
  unsigned short* W_fpw      = Wb + 21*(size_t)WSLOT;
  unsigned short* W_pproj    = Wb + 33*(size_t)WSLOT;
  unsigned short* W_fproj    = W_pproj + 4*(size_t)PSW;

  transpose_x_k<<<g32, b256, 0, stream>>>(x, xT);

  // ---- h path ----
  conv_cc_k<<<g32, b256, 0, stream>>>(xT, W_pre, pre_b, mask, nullptr, A, 0);
  mega_dds_k<<<g32, b256, 0, stream>>>(A, nullptr, 0, nullptr, Bb, mask,
      dds_dep_w, dds_dep_b, dds_ln_g, dds_ln_b, dds_pw_b, nullptr, nullptr,
      W_dds, 0, 0, nullptr, nullptr, nullptr, 0, acc);
  conv_cc_k<<<g32, b256, 0, stream>>>(Bb, W_proj, proj_b, mask, nullptr, H, 1);

  // ---- hw path ----
  mega_dds_k<<<g32, b256, 0, stream>>>(nullptr, w_in, TTT, nullptr, A, mask,
      pdds_dep_w, pdds_dep_b, pdds_ln_g, pdds_ln_b, pdds_pw_b, post_pre_w, post_pre_b,
      W_pdds, 1, 0, nullptr, nullptr, nullptr, 0, acc);
  conv_cc_k<<<g32, b256, 0, stream>>>(A, W_postproj, post_proj_b, mask, H, GP, 2);

  // ---- init z ----
  init_z_k<<<g256, b256, 0, stream>>>(e_q, mask, paff_m, paff_logs, zbuf, acc);

  // ---- 4 posterior flows (g = GP) ----
  for (int f=0; f<4; f++){
    int s = f & 1;
    mega_dds_k<<<g32, b256, 0, stream>>>(nullptr, zbuf + (size_t)s*TTT, 2*TTT, GP, nullptr, mask,
        p_dep_w + (size_t)f*3*CC*3, p_dep_b + (size_t)f*3*CC,
        p_ln_g + (size_t)f*3*2*CC, p_ln_b + (size_t)f*3*2*CC,
        p_pw_b + (size_t)f*3*CC,
        p_pre_w + (size_t)f*CC, p_pre_b + (size_t)f*CC,
        W_ppw + (size_t)f*3*WSLOT, 1, 1,
        W_pproj + (size_t)f*PSW, p_proj_b + (size_t)f*PP, zbuf, s, acc);
  }

  // ---- transition ----
  final_pre_k<<<g256, b256, 0, stream>>>(zbuf, w_in, mask, aff_m, aff_logs, acc);

  // ---- 4 flows (g = H) ----
  for (int f=0; f<4; f++){
    int s = f & 1;
    mega_dds_k<<<g32, b256, 0, stream>>>(nullptr, zbuf + (size_t)s*TTT, 2*TTT, H, nullptr, mask,
        f_dep_w + (size_t)f*3*CC*3, f_dep_b + (size_t)f*3*CC,
        f_ln_g + (size_t)f*3*2*CC, f_ln_b + (size_t)f*3*2*CC,
        f_pw_b + (size_t)f*3*CC,
        f_pre_w + (size_t)f*CC, f_pre_b + (size_t)f*CC,
        W_fpw + (size_t)f*3*WSLOT, 1, 1,
        W_fproj + (size_t)f*PSW, f_proj_b + (size_t)f*PP, zbuf, s, acc);
  }

  final_post_k<<<g256, b256, 0, stream>>>(zbuf, mask, acc);
  write_out_k<<<1, 64, 0, stream>>>(acc, (float*)d_out, Bn);
}

// Round 7
// 961.947 us; speedup vs baseline: 1.3242x; 1.0344x over previous
//
#include <hip/hip_runtime.h>
#include <math.h>

#define CC 192
#define TTT 768
#define PP 29
#define LOG2PI_F 1.8378770664093453f
#define WSLOT 36864   // swizzled 192x192 slot (elements)
#define PSW 6144      // swizzled 32x192 proj slot (elements)
#define XS 200        // ushort stride for conv_cc/transpose LDS tiles
#define XS2 196       // ushort stride for mega ping (392B rows: b64 4-way max)

typedef __attribute__((ext_vector_type(8))) short short8;
typedef __attribute__((ext_vector_type(4))) float floatx4;
typedef __attribute__((ext_vector_type(2))) float float2v;
union Frag { int4 i; short8 s; };

__device__ __forceinline__ float2v fma2(float2v a, float2v b, float2v c){
  return __builtin_elementwise_fma(a, b, c);
}
__device__ __forceinline__ float geluf(float x){
  float u = 1.5957691216057308f * (x + 0.044715f*x*x*x);
  return x * __builtin_amdgcn_rcpf(1.f + __expf(-u));
}
__device__ __forceinline__ float softplus_f(float x){
  return (x > 20.f) ? x : log1pf(__expf(x));
}
__device__ __forceinline__ float logsig_f(float x){
  return -softplus_f(-x);
}
__device__ __forceinline__ unsigned short f2bf(float f){
  unsigned int u = __builtin_bit_cast(unsigned int, f);
  u += 0x7fffu + ((u >> 16) & 1u);
  return (unsigned short)(u >> 16);
}
__device__ __forceinline__ unsigned int packbf2(float a0, float a1){
  return (unsigned int)f2bf(a0) | ((unsigned int)f2bf(a1) << 16);
}
__device__ __forceinline__ void unbf2(unsigned int u, float& lo, float& hi){
  lo = __builtin_bit_cast(float, u << 16);
  hi = __builtin_bit_cast(float, u & 0xffff0000u);
}
__device__ __forceinline__ float2v unbf2v(unsigned int u){
  float2v r;
  r.x = __builtin_bit_cast(float, u << 16);
  r.y = __builtin_bit_cast(float, u & 0xffff0000u);
  return r;
}
__device__ __forceinline__ void unp8(int4 v, float* o){
  unsigned int* p = (unsigned int*)&v;
  unbf2(p[0], o[0], o[1]); unbf2(p[1], o[2], o[3]);
  unbf2(p[2], o[4], o[5]); unbf2(p[3], o[6], o[7]);
}
__device__ __forceinline__ void f4arr(float4 v, float* o){ o[0]=v.x;o[1]=v.y;o[2]=v.z;o[3]=v.w; }

// ---------------- weight f32 -> bf16 swizzled fragment order ----------------
__global__ __launch_bounds__(256) void convert_w_k(
    const float* __restrict__ p0, const float* __restrict__ p1,
    const float* __restrict__ p2, const float* __restrict__ p3,
    const float* __restrict__ p4, const float* __restrict__ p5,
    const float* __restrict__ p6, const float* __restrict__ p7,
    const float* __restrict__ p8, unsigned short* __restrict__ Wb){
  int i = blockIdx.x*256 + threadIdx.x;
  const int totalA = 33*WSLOT;
  const int total = totalA + 8*PSW;
  if (i >= total) return;
  if (i < totalA){
    int slot = i / WSLOT, j = i % WSLOT;
    int e = j & 7, lane = (j>>3) & 63, kt = j >> 9;
    int k = kt % 6, tile = kt / 6;
    int co = tile*16 + (lane & 15);
    int kk = k*32 + (lane>>4)*8 + e;
    int r = co*CC + kk;
    const float* src;
    if      (slot == 0) src = p0 + r;
    else if (slot == 1) src = p1 + r;
    else if (slot == 2) src = p2 + r;
    else if (slot < 6)  src = p3 + (size_t)(slot-3)*WSLOT + r;
    else if (slot < 9)  src = p4 + (size_t)(slot-6)*WSLOT + r;
    else if (slot < 21) src = p5 + (size_t)(slot-9)*WSLOT + r;
    else                src = p6 + (size_t)(slot-21)*WSLOT + r;
    Wb[i] = f2bf(*src);
  } else {
    int r2 = i - totalA;
    int ps = r2 / PSW, j = r2 % PSW;
    int e = j & 7, lane = (j>>3) & 63, kt = j >> 9;
    int k = kt % 6, tile = kt / 6;
    int co = tile*16 + (lane & 15); if (co > PP-1) co = PP-1;
    int kk = k*32 + (lane>>4)*8 + e;
    const float* base = (ps < 4) ? (p7 + (size_t)ps*PP*CC) : (p8 + (size_t)(ps-4)*PP*CC);
    Wb[i] = f2bf(base[co*CC + kk]);
  }
}

// ---------------- x f32 [B][C][T] -> bf16 [B][T][C] ----------------
__global__ __launch_bounds__(256) void transpose_x_k(
    const float* __restrict__ x, unsigned short* __restrict__ xT){
  __shared__ unsigned short tile[32*XS];
  int b = blockIdx.y, t0 = blockIdx.x*32, tid = threadIdx.x;
  int tl4 = (tid & 7)*4, cr = tid >> 3;
  #pragma unroll
  for (int rnd=0; rnd<6; rnd++){
    int c = rnd*32 + cr;
    float4 v4 = *(const float4*)(x + ((size_t)b*CC + c)*TTT + t0 + tl4);
    tile[(tl4+0)*XS + c] = f2bf(v4.x);
    tile[(tl4+1)*XS + c] = f2bf(v4.y);
    tile[(tl4+2)*XS + c] = f2bf(v4.z);
    tile[(tl4+3)*XS + c] = f2bf(v4.w);
  }
  __syncthreads();
  #pragma unroll
  for (int k=0;k<3;k++){
    int task = k*256 + tid;
    int row = task/24, cn = task%24;
    *(int4*)(xT + ((size_t)b*TTT + t0 + row)*CC + cn*8) = *(const int4*)&tile[row*XS + cn*8];
  }
}

// ---------------- conv 192x192 bf16 MFMA, t-major bf16 in/out ----------------
__global__ __launch_bounds__(256) void conv_cc_k(
    const unsigned short* __restrict__ in, const unsigned short* __restrict__ Wsw,
    const float* __restrict__ bias, const float* __restrict__ mask,
    const unsigned short* __restrict__ addsrc, unsigned short* __restrict__ outb, int mode){
  __shared__ unsigned short bufX[32*XS];
  __shared__ unsigned short bufY[32*XS];
  __shared__ float marr[32];
  int b = blockIdx.y, t0 = blockIdx.x*32, tid = threadIdx.x;
  #pragma unroll
  for (int k=0;k<3;k++){
    int task = k*256 + tid;
    int row = task/24, cn = task%24;
    const unsigned short* src = in + ((size_t)b*TTT + t0 + row)*CC + cn*8;
    *(int4*)&bufX[row*XS + cn*8] = *(const int4*)src;
    if (mode == 2){
      const unsigned short* s2 = addsrc + ((size_t)b*TTT + t0 + row)*CC + cn*8;
      *(int4*)&bufY[row*XS + cn*8] = *(const int4*)s2;
    }
  }
  if (tid >= 128 && tid < 160) marr[tid-128] = mask[(size_t)b*TTT + t0 + (tid-128)];
  __syncthreads();
  int w = tid >> 6, lane = tid & 63;
  int n16 = lane & 15, quad = lane >> 4;
  Frag af[3][6];
  #pragma unroll
  for (int ct=0; ct<3; ct++){
    int tile = w*3 + ct;
    #pragma unroll
    for (int k=0;k<6;k++)
      af[ct][k].i = *(const int4*)(Wsw + ((size_t)(tile*6 + k)*64 + lane)*8);
  }
  floatx4 acc[3][2];
  #pragma unroll
  for (int ct=0;ct<3;ct++)
    #pragma unroll
    for (int tt=0;tt<2;tt++)
      acc[ct][tt] = (floatx4){0.f,0.f,0.f,0.f};
  #pragma unroll
  for (int k=0;k<6;k++){
    Frag bf[2];
    #pragma unroll
    for (int tt=0;tt<2;tt++)
      bf[tt].i = *(const int4*)&bufX[(tt*16+n16)*XS + k*32 + quad*8];
    #pragma unroll
    for (int ct=0;ct<3;ct++)
      #pragma unroll
      for (int tt=0;tt<2;tt++)
        acc[ct][tt] = __builtin_amdgcn_mfma_f32_16x16x32_bf16(af[ct][k].s, bf[tt].s, acc[ct][tt], 0,0,0);
  }
  __syncthreads();
  #pragma unroll
  for (int ct=0;ct<3;ct++){
    int cobase = w*48 + ct*16 + quad*4;
    float4 b4 = *(const float4*)(bias + cobase);
    float ba[4] = {b4.x, b4.y, b4.z, b4.w};
    #pragma unroll
    for (int tt=0;tt<2;tt++){
      int t = tt*16 + n16;
      float mv = (mode >= 1) ? marr[t] : 1.f;
      float av[4] = {0.f,0.f,0.f,0.f};
      if (mode == 2){
        uint2 uy = *(uint2*)&bufY[t*XS + cobase];
        unbf2(uy.x, av[0], av[1]); unbf2(uy.y, av[2], av[3]);
      }
      float hh[4];
      #pragma unroll
      for (int r=0;r<4;r++){
        float v = acc[ct][tt][r] + ba[r];
        if (mode >= 1) v *= mv;
        if (mode == 2) v += av[r];
        hh[r] = v;
      }
      uint2 wv; wv.x = packbf2(hh[0], hh[1]); wv.y = packbf2(hh[2], hh[3]);
      *(uint2*)&bufX[t*XS + cobase] = wv;
    }
  }
  __syncthreads();
  #pragma unroll
  for (int k=0;k<3;k++){
    int task = k*256 + tid;
    int row = task/24, cn = task%24;
    *(int4*)(outb + ((size_t)b*TTT + t0 + row)*CC + cn*8) = *(const int4*)&bufX[row*XS + cn*8];
  }
}

// ---------------- mega DDS v2: wave-per-t-tile, B-frags in registers ----------------
// srcmode 0: x from `in` (bf16 t-major), pre-masked at staging
// srcmode 1: x = (pw1*z + pb1 (+ g)) * mask
// outmode 0: write center 32 rows to outb; outmode 1: proj + RQS spline
__global__ __launch_bounds__(256,4) void mega_dds_k(
    const unsigned short* __restrict__ in,
    const float* __restrict__ zsrc, int zstride,
    const unsigned short* __restrict__ g,
    unsigned short* __restrict__ outb,
    const float* __restrict__ mask,
    const float* __restrict__ dwB, const float* __restrict__ dbB,
    const float* __restrict__ lngB, const float* __restrict__ lnbB,
    const float* __restrict__ pwbB,
    const float* __restrict__ pw1, const float* __restrict__ pb1,
    const unsigned short* __restrict__ Wsw,
    int srcmode, int outmode,
    const unsigned short* __restrict__ projW, const float* __restrict__ projB,
    float* __restrict__ z, int zs, float* __restrict__ acco){
  __shared__ unsigned short ping[64*XS2];   // bf16 [window row][c], in-place residual stream
  __shared__ float mrow[64];
  __shared__ float pro[32*30];

  int b = blockIdx.y, t0 = blockIdx.x*32, tid = threadIdx.x;
  int ws0 = t0 - 16;
  int w = tid >> 6, lane = tid & 63;
  int n16 = lane & 15, quad = lane >> 4;
  int row = w*16 + n16;                      // this lane's window row
  const float* mkb = mask + (size_t)b*TTT;
  const int dils[3] = {1,3,9};

  if (tid < 64){
    int gt = ws0 + tid;
    bool inr = (gt >= 0) && (gt < TTT);
    int gc = gt < 0 ? 0 : (gt > TTT-1 ? TTT-1 : gt);
    mrow[tid] = inr ? mkb[gc] : 0.f;
  }
  // ---- staging (pre-masked) ----
  if (srcmode == 0){
    #pragma unroll
    for (int k=0;k<6;k++){
      int task = k*256 + tid;
      int r = task/24, cn = task%24, c0 = cn*8;
      int gt = ws0 + r;
      bool inr = (gt >= 0) && (gt < TTT);
      int gc = gt < 0 ? 0 : (gt > TTT-1 ? TTT-1 : gt);
      float mv = inr ? mkb[gc] : 0.f;
      float hv[8];
      unp8(*(const int4*)(in + ((size_t)b*TTT + gc)*CC + c0), hv);
      uint2 w0, w1;
      w0.x = packbf2(hv[0]*mv, hv[1]*mv); w0.y = packbf2(hv[2]*mv, hv[3]*mv);
      w1.x = packbf2(hv[4]*mv, hv[5]*mv); w1.y = packbf2(hv[6]*mv, hv[7]*mv);
      *(uint2*)&ping[r*XS2 + c0]     = w0;
      *(uint2*)&ping[r*XS2 + c0 + 4] = w1;
    }
  } else {
    #pragma unroll
    for (int k=0;k<6;k++){
      int task = k*256 + tid;
      int r = task/24, cn = task%24, c0 = cn*8;
      int gt = ws0 + r;
      bool inr = (gt >= 0) && (gt < TTT);
      int gc = gt < 0 ? 0 : (gt > TTT-1 ? TTT-1 : gt);
      float mv = inr ? mkb[gc] : 0.f;
      float zv = inr ? zsrc[(size_t)b*zstride + gc] : 0.f;
      float hv[8];
      if (g){
        unp8(*(const int4*)(g + ((size_t)b*TTT + gc)*CC + c0), hv);
      } else {
        #pragma unroll
        for (int e=0;e<8;e++) hv[e] = 0.f;
      }
      float4 pwa = *(const float4*)(pw1 + c0);
      float4 pwb2 = *(const float4*)(pw1 + c0 + 4);
      float4 pba = *(const float4*)(pb1 + c0);
      float4 pbb2 = *(const float4*)(pb1 + c0 + 4);
      float pwv[8], pbv[8];
      f4arr(pwa, pwv); f4arr(pwb2, pwv+4);
      f4arr(pba, pbv); f4arr(pbb2, pbv+4);
      float ov[8];
      #pragma unroll
      for (int e=0;e<8;e++) ov[e] = (hv[e] + fmaf(pwv[e], zv, pbv[e]))*mv;
      uint2 w0, w1;
      w0.x = packbf2(ov[0], ov[1]); w0.y = packbf2(ov[2], ov[3]);
      w1.x = packbf2(ov[4], ov[5]); w1.y = packbf2(ov[6], ov[7]);
      *(uint2*)&ping[r*XS2 + c0]     = w0;
      *(uint2*)&ping[r*XS2 + c0 + 4] = w1;
    }
  }
  __syncthreads();

  // ---- 3 fused layers ----
  #pragma unroll
  for (int l=0; l<3; l++){
    const int dil = dils[l];
    const bool active = (l < 2) || (w == 1) || (w == 2);
    Frag bfr[6];
    float cmP, crP;                 // conv-LN stats (post-conv), per-row
    floatx4 acc[12];
    if (active){
      int iL = row - dil; iL = iL < 0 ? 0 : iL;
      int iR = row + dil; iR = iR > 63 ? 63 : iR;
      const float* dwl = dwB + l*CC*3;
      const float* dbl = dbB + l*CC;
      float2v vv[24];
      float s = 0.f, q = 0.f;
      #pragma unroll
      for (int j=0;j<6;j++){
        int kk = j*32 + quad*8;
        uint2 a0 = *(uint2*)&ping[iL*XS2 + kk], a1 = *(uint2*)&ping[iL*XS2 + kk + 4];
        uint2 b0 = *(uint2*)&ping[row*XS2 + kk], b1 = *(uint2*)&ping[row*XS2 + kk + 4];
        uint2 c0v = *(uint2*)&ping[iR*XS2 + kk], c1 = *(uint2*)&ping[iR*XS2 + kk + 4];
        float2v XL[4] = {unbf2v(a0.x), unbf2v(a0.y), unbf2v(a1.x), unbf2v(a1.y)};
        float2v XC[4] = {unbf2v(b0.x), unbf2v(b0.y), unbf2v(b1.x), unbf2v(b1.y)};
        float2v XR[4] = {unbf2v(c0v.x), unbf2v(c0v.y), unbf2v(c1.x), unbf2v(c1.y)};
        #pragma unroll
        for (int p=0;p<4;p++){
          int cc = kk + 2*p;
          float2v w0 = {dwl[cc*3+0], dwl[cc*3+3]};
          float2v w1 = {dwl[cc*3+1], dwl[cc*3+4]};
          float2v w2 = {dwl[cc*3+2], dwl[cc*3+5]};
          float2v bb = {dbl[cc], dbl[cc+1]};
          float2v val = fma2(w0, XL[p], fma2(w1, XC[p], fma2(w2, XR[p], bb)));
          vv[j*4+p] = val;
          s += val.x + val.y;
          q = fmaf(val.x, val.x, fmaf(val.y, val.y, q));
        }
      }
      s += __shfl_xor(s, 16); s += __shfl_xor(s, 32);
      q += __shfl_xor(q, 16); q += __shfl_xor(q, 32);
      float mm = s*(1.f/CC);
      float rr = rsqrtf(q*(1.f/CC) - mm*mm + 1e-5f);
      // P3: LN + gelu -> B fragments in registers
      {
        const float* g0p = lngB + (l*2)*CC;
        const float* b0p = lnbB + (l*2)*CC;
        float2v mm2 = {mm,mm}, rr2 = {rr,rr};
        #pragma unroll
        for (int j=0;j<6;j++){
          int kk = j*32 + quad*8;
          unsigned int wwp[4];
          #pragma unroll
          for (int p=0;p<4;p++){
            int cc = kk + 2*p;
            float2v a = fma2((vv[j*4+p]-mm2)*rr2, (float2v){g0p[cc], g0p[cc+1]},
                             (float2v){b0p[cc], b0p[cc+1]});
            wwp[p] = packbf2(geluf(a.x), geluf(a.y));
          }
          bfr[j].i = make_int4((int)wwp[0], (int)wwp[1], (int)wwp[2], (int)wwp[3]);
        }
      }
    }
    __syncthreads();   // all P1 ping reads done before in-place P6 writes
    if (active){
      // P4: stream all 12 A-tiles, B from registers
      const unsigned short* WL = Wsw + (size_t)l*WSLOT;
      #pragma unroll
      for (int tile=0; tile<12; tile++){
        acc[tile] = (floatx4){0.f,0.f,0.f,0.f};
        Frag af[6];
        #pragma unroll
        for (int k=0;k<6;k++)
          af[k].i = *(const int4*)(WL + ((size_t)(tile*6 + k)*64 + lane)*8);
        #pragma unroll
        for (int k=0;k<6;k++)
          acc[tile] = __builtin_amdgcn_mfma_f32_16x16x32_bf16(af[k].s, bfr[k].s, acc[tile], 0,0,0);
      }
      // bias + conv-LN stats (in-wave)
      const float* pbp = pwbB + l*CC;
      float s2 = 0.f, q2 = 0.f;
      #pragma unroll
      for (int tile=0; tile<12; tile++){
        int co = tile*16 + quad*4;
        float4 pbv = *(const float4*)(pbp + co);
        float pba[4]; f4arr(pbv, pba);
        #pragma unroll
        for (int r=0;r<4;r++){
          acc[tile][r] += pba[r];
          float x = acc[tile][r];
          s2 += x; q2 = fmaf(x, x, q2);
        }
      }
      s2 += __shfl_xor(s2, 16); s2 += __shfl_xor(s2, 32);
      q2 += __shfl_xor(q2, 16); q2 += __shfl_xor(q2, 32);
      cmP = s2*(1.f/CC);
      crP = rsqrtf(q2*(1.f/CC) - cmP*cmP + 1e-5f);
      // P6: LN + gelu + residual, in-place (each 8B owned by one lane)
      const float* g1p = lngB + (l*2+1)*CC;
      const float* b1p = lnbB + (l*2+1)*CC;
      float2v cm2 = {cmP,cmP}, cr2 = {crP,crP};
      #pragma unroll
      for (int tile=0; tile<12; tile++){
        int co = tile*16 + quad*4;
        uint2 ux = *(uint2*)&ping[row*XS2 + co];
        float2v x01 = unbf2v(ux.x), x23 = unbf2v(ux.y);
        float2v v01 = {acc[tile][0], acc[tile][1]};
        float2v v23 = {acc[tile][2], acc[tile][3]};
        float2v a01 = fma2((v01-cm2)*cr2, (float2v){g1p[co],   g1p[co+1]},
                           (float2v){b1p[co],   b1p[co+1]});
        float2v a23 = fma2((v23-cm2)*cr2, (float2v){g1p[co+2], g1p[co+3]},
                           (float2v){b1p[co+2], b1p[co+3]});
        uint2 wv;
        wv.x = packbf2(x01.x + geluf(a01.x), x01.y + geluf(a01.y));
        wv.y = packbf2(x23.x + geluf(a23.x), x23.y + geluf(a23.y));
        *(uint2*)&ping[row*XS2 + co] = wv;
      }
    }
    __syncthreads();   // P6 writes visible before next layer's P1
  }

  if (outmode == 0){
    #pragma unroll
    for (int k=0;k<3;k++){
      int task = k*256 + tid;
      int r = task/24, cn = task%24, c0 = cn*8;
      uint2 u0 = *(uint2*)&ping[(16+r)*XS2 + c0];
      uint2 u1 = *(uint2*)&ping[(16+r)*XS2 + c0 + 4];
      *(int4*)(outb + ((size_t)b*TTT + t0 + r)*CC + c0) =
          make_int4((int)u0.x, (int)u0.y, (int)u1.x, (int)u1.y);
    }
    return;
  }

  // ---- proj (29x192) on center rows: waves 1,2 own rows 16..47 ----
  if (w == 1 || w == 2){
    int prow = row;                     // 16..47
    Frag bfp[6];
    #pragma unroll
    for (int k=0;k<6;k++){
      int kk = k*32 + quad*8;
      uint2 u0 = *(uint2*)&ping[prow*XS2 + kk];
      uint2 u1 = *(uint2*)&ping[prow*XS2 + kk + 4];
      bfp[k].i = make_int4((int)u0.x, (int)u0.y, (int)u1.x, (int)u1.y);
    }
    floatx4 acc2[2];
    acc2[0] = (floatx4){0.f,0.f,0.f,0.f};
    acc2[1] = (floatx4){0.f,0.f,0.f,0.f};
    #pragma unroll
    for (int ct2=0; ct2<2; ct2++){
      #pragma unroll
      for (int k=0;k<6;k++){
        Frag af;
        af.i = *(const int4*)(projW + ((size_t)(ct2*6 + k)*64 + lane)*8);
        acc2[ct2] = __builtin_amdgcn_mfma_f32_16x16x32_bf16(af.s, bfp[k].s, acc2[ct2], 0,0,0);
      }
    }
    int rt = row - 16;                  // 0..31
    float mv = mrow[row];
    #pragma unroll
    for (int ct2=0; ct2<2; ct2++){
      int cobase = ct2*16 + quad*4;
      #pragma unroll
      for (int r=0;r<4;r++){
        int co = cobase + r;
        if (co < PP) pro[rt*30 + co] = (acc2[ct2][r] + projB[co]) * mv;
      }
    }
  }
  __syncthreads();
  // ---- RQS spline on 32 lanes ----
  if (tid < 32){
    const float scv = 0.07216878364870323f;   // 1/sqrt(192)
    int tg = t0 + tid;
    float m = mrow[16+tid];
    float* z0p = z + ((size_t)b*2 + zs)*TTT + tg;
    float* z1p = z + ((size_t)b*2 + (1-zs))*TTT + tg;
    float xs = *z1p;
    float uw[10], uh[10], ud[9];
    #pragma unroll
    for (int k=0;k<10;k++) uw[k]=pro[tid*30+k]*scv;
    #pragma unroll
    for (int k=0;k<10;k++) uh[k]=pro[tid*30+10+k]*scv;
    #pragma unroll
    for (int k=0;k<9;k++)  ud[k]=pro[tid*30+20+k];
    bool inside = (xs >= -5.f) && (xs <= 5.f);
    float xc = fminf(fmaxf(xs,-5.f),5.f);
    float mx=uw[0];
    #pragma unroll
    for (int k=1;k<10;k++) mx=fmaxf(mx,uw[k]);
    float sw=0.f; float wd[10];
    #pragma unroll
    for (int k=0;k<10;k++){ wd[k]=__expf(uw[k]-mx); sw+=wd[k]; }
    float invw = 1.f/sw;
    #pragma unroll
    for (int k=0;k<10;k++) wd[k]=fmaf(0.99f*invw, wd[k], 1e-3f);
    float mh=uh[0];
    #pragma unroll
    for (int k=1;k<10;k++) mh=fmaxf(mh,uh[k]);
    float sh=0.f; float ht[10];
    #pragma unroll
    for (int k=0;k<10;k++){ ht[k]=__expf(uh[k]-mh); sh+=ht[k]; }
    float invh = 1.f/sh;
    #pragma unroll
    for (int k=0;k<10;k++) ht[k]=fmaf(0.99f*invh, ht[k], 1e-3f);
    float cw=-5.f, icw=-5.f, iw=1.f; int idx=0;
    #pragma unroll
    for (int i2=0;i2<10;i2++){
      float nw = (i2==9) ? 5.f : fmaf(10.f, wd[i2], cw);
      if (cw <= xc){ idx=i2; icw=cw; iw=nw-cw; }
      cw=nw;
    }
    float ch=-5.f, ich=-5.f, ih=1.f;
    #pragma unroll
    for (int i2=0;i2<10;i2++){
      float nh = (i2==9) ? 5.f : fmaf(10.f, ht[i2], ch);
      if (i2==idx){ ich=ch; ih=nh-ch; }
      ch=nh;
    }
    const float UDC = logf(expm1f(0.999f));
    float d0=1.f, d1=1.f;
    #pragma unroll
    for (int k=0;k<11;k++){
      float uu = (k==0 || k==10) ? UDC : ud[k-1];
      float dk = 1e-3f + softplus_f(uu);
      if (k==idx)   d0=dk;
      if (k==idx+1) d1=dk;
    }
    float idel = ih/iw;
    float th = (xc-icw)/iw;
    float t1m = th*(1.f-th);
    float den = idel + (d0+d1-2.f*idel)*t1m;
    float outv = ich + ih*(idel*th*th + d0*t1m)/den;
    float omt = 1.f-th;
    float dnum = idel*idel*(d1*th*th + 2.f*idel*t1m + d0*omt*omt);
    float lad = logf(dnum) - 2.f*logf(den);
    float y = inside ? outv : xs;
    lad = inside ? lad : 0.f;
    *z1p = y*m;
    *z0p = (*z0p)*m;
    float lm = lad*m;
    lm += __shfl_xor(lm, 1); lm += __shfl_xor(lm, 2);
    lm += __shfl_xor(lm, 4); lm += __shfl_xor(lm, 8);
    lm += __shfl_xor(lm, 16);
    if (tid == 0) atomicAdd(acco + b, -lm);
  }
}

// ---------------- z init ----------------
__global__ __launch_bounds__(256) void init_z_k(
    const float* __restrict__ e_q, const float* __restrict__ mask,
    const float* __restrict__ pm, const float* __restrict__ pl,
    float* __restrict__ z, float* __restrict__ acc){
  __shared__ float red[256];
  int b = blockIdx.y; int t = blockIdx.x*256 + threadIdx.x;
  float m = mask[(size_t)b*TTT + t];
  float pl0=pl[0], pl1=pl[1];
  float e0 = e_q[((size_t)b*2+0)*TTT + t]*m;
  float e1 = e_q[((size_t)b*2+1)*TTT + t]*m;
  z[((size_t)b*2+0)*TTT + t] = fmaf(__expf(pl0), e0, pm[0])*m;
  z[((size_t)b*2+1)*TTT + t] = fmaf(__expf(pl1), e1, pm[1])*m;
  float contrib = -0.5f*(LOG2PI_F + e0*e0)*m - 0.5f*(LOG2PI_F + e1*e1)*m - (pl0+pl1)*m;
  int tid = threadIdx.x;
  red[tid] = contrib;
  __syncthreads();
  for (int o=128;o>0;o>>=1){ if (tid<o) red[tid]+=red[tid+o]; __syncthreads(); }
  if (tid==0) atomicAdd(acc+b, red[0]);
}

// ---------------- between p-flows and f-flows ----------------
__global__ __launch_bounds__(256) void final_pre_k(
    float* __restrict__ z, const float* __restrict__ w_in, const float* __restrict__ mask,
    const float* __restrict__ am, const float* __restrict__ al, float* __restrict__ acc){
  __shared__ float red[256];
  int b = blockIdx.y; int t = blockIdx.x*256 + threadIdx.x;
  float m = mask[(size_t)b*TTT + t];
  float zu  = z[((size_t)b*2+0)*TTT + t];
  float z1v = z[((size_t)b*2+1)*TTT + t];
  float wv  = w_in[(size_t)b*TTT + t];
  float u  = m / (1.f + __expf(-zu));
  float z0 = (wv - u)*m;
  float y0 = logf(fmaxf(z0, 1e-5f))*m;
  float al0=al[0], al1=al[1];
  z[((size_t)b*2+0)*TTT + t] = fmaf(__expf(al0), y0,  am[0])*m;
  z[((size_t)b*2+1)*TTT + t] = fmaf(__expf(al1), z1v, am[1])*m;
  float contrib = -(logsig_f(zu)+logsig_f(-zu))*m + y0 - (al0+al1)*m;
  int tid = threadIdx.x;
  red[tid] = contrib;
  __syncthreads();
  for (int o=128;o>0;o>>=1){ if (tid<o) red[tid]+=red[tid+o]; __syncthreads(); }
  if (tid==0) atomicAdd(acc+b, red[0]);
}

// ---------------- final 0.5(log2pi + z^2) sum ----------------
__global__ __launch_bounds__(256) void final_post_k(
    const float* __restrict__ z, const float* __restrict__ mask, float* __restrict__ acc){
  __shared__ float red[256];
  int b = blockIdx.y; int t = blockIdx.x*256 + threadIdx.x;
  float m = mask[(size_t)b*TTT + t];
  float z0 = z[((size_t)b*2+0)*TTT + t];
  float z1 = z[((size_t)b*2+1)*TTT + t];
  float contrib = 0.5f*(LOG2PI_F + z0*z0)*m + 0.5f*(LOG2PI_F + z1*z1)*m;
  int tid = threadIdx.x;
  red[tid] = contrib;
  __syncthreads();
  for (int o=128;o>0;o>>=1){ if (tid<o) red[tid]+=red[tid+o]; __syncthreads(); }
  if (tid==0) atomicAdd(acc+b, red[0]);
}

__global__ void write_out_k(const float* __restrict__ acc, float* __restrict__ out, int n){
  int i = threadIdx.x;
  if (i < n) out[i] = acc[i];
}

extern "C" void kernel_launch(void* const* d_in, const int* in_sizes, int n_in,
                              void* d_out, int out_size, void* d_ws, size_t ws_size,
                              hipStream_t stream){
  (void)n_in; (void)out_size; (void)ws_size;
  const float* x         = (const float*)d_in[0];
  const float* mask      = (const float*)d_in[1];
  const float* w_in      = (const float*)d_in[2];
  const float* e_q       = (const float*)d_in[3];
  const float* pre_w     = (const float*)d_in[4];
  const float* pre_b     = (const float*)d_in[5];
  const float* proj_w    = (const float*)d_in[6];
  const float* proj_b    = (const float*)d_in[7];
  const float* dds_dep_w = (const float*)d_in[8];
  const float* dds_dep_b = (const float*)d_in[9];
  const float* dds_pw_w  = (const float*)d_in[10];
  const float* dds_pw_b  = (const float*)d_in[11];
  const float* dds_ln_g  = (const float*)d_in[12];
  const float* dds_ln_b  = (const float*)d_in[13];
  const float* post_pre_w  = (const float*)d_in[14];
  const float* post_pre_b  = (const float*)d_in[15];
  const float* post_proj_w = (const float*)d_in[16];
  const float* post_proj_b = (const float*)d_in[17];
  const float* pdds_dep_w  = (const float*)d_in[18];
  const float* pdds_dep_b  = (const float*)d_in[19];
  const float* pdds_pw_w   = (const float*)d_in[20];
  const float* pdds_pw_b   = (const float*)d_in[21];
  const float* pdds_ln_g   = (const float*)d_in[22];
  const float* pdds_ln_b   = (const float*)d_in[23];
  const float* aff_m    = (const float*)d_in[24];
  const float* aff_logs = (const float*)d_in[25];
  const float* f_pre_w  = (const float*)d_in[26];
  const float* f_pre_b  = (const float*)d_in[27];
  const float* f_dep_w  = (const float*)d_in[28];
  const float* f_dep_b  = (const float*)d_in[29];
  const float* f_pw_w   = (const float*)d_in[30];
  const float* f_pw_b   = (const float*)d_in[31];
  const float* f_ln_g   = (const float*)d_in[32];
  const float* f_ln_b   = (const float*)d_in[33];
  const float* f_proj_w = (const float*)d_in[34];
  const float* f_proj_b = (const float*)d_in[35];
  const float* paff_m    = (const float*)d_in[36];
  const float* paff_logs = (const float*)d_in[37];
  const float* p_pre_w  = (const float*)d_in[38];
  const float* p_pre_b  = (const float*)d_in[39];
  const float* p_dep_w  = (const float*)d_in[40];
  const float* p_dep_b  = (const float*)d_in[41];
  const float* p_pw_w   = (const float*)d_in[42];
  const float* p_pw_b   = (const float*)d_in[43];
  const float* p_ln_g   = (const float*)d_in[44];
  const float* p_ln_b   = (const float*)d_in[45];
  const float* p_proj_w = (const float*)d_in[46];
  const float* p_proj_b = (const float*)d_in[47];

  int Bn = in_sizes[0] / (CC*TTT);
  size_t big2 = (size_t)Bn*CC*TTT;
  unsigned short* xT = (unsigned short*)d_ws;
  unsigned short* A  = xT + big2;
  unsigned short* Bb = A  + big2;
  unsigned short* H  = Bb + big2;
  unsigned short* GP = H  + big2;
  unsigned short* Wb = GP + big2;
  size_t wtot = 33*(size_t)WSLOT + 8*(size_t)PSW;
  float* zbuf = (float*)(Wb + ((wtot + 7) & ~(size_t)7));
  float* acc  = zbuf + (size_t)Bn*2*TTT;

  hipMemsetAsync(acc, 0, Bn*sizeof(float), stream);
  convert_w_k<<<(int)((wtot + 255)/256), 256, 0, stream>>>(
      pre_w, proj_w, post_proj_w, dds_pw_w, pdds_pw_w, p_pw_w, f_pw_w,
      p_proj_w, f_proj_w, Wb);

  dim3 g32(TTT/32, Bn), g256(TTT/256, Bn);
  dim3 b256(256);

  unsigned short* W_pre      = Wb + 0*(size_t)WSLOT;
  unsigned short* W_proj     = Wb + 1*(size_t)WSLOT;
  unsigned short* W_postproj = Wb + 2*(size_t)WSLOT;
  unsigned short* W_dds      = Wb + 3*(size_t)WSLOT;
  unsigned short* W_pdds     = Wb + 6*(size_t)WSLOT;
  unsigned short* W_ppw      = Wb + 9*(size_t)WSLOT;
  unsigned short* W_fpw      = Wb + 21*(size_t)WSLOT;
  unsigned short* W_pproj    = Wb + 33*(size_t)WSLOT;
  unsigned short* W_fproj    = W_pproj + 4*(size_t)PSW;

  transpose_x_k<<<g32, b256, 0, stream>>>(x, xT);

  // ---- h path ----
  conv_cc_k<<<g32, b256, 0, stream>>>(xT, W_pre, pre_b, mask, nullptr, A, 0);
  mega_dds_k<<<g32, b256, 0, stream>>>(A, nullptr, 0, nullptr, Bb, mask,
      dds_dep_w, dds_dep_b, dds_ln_g, dds_ln_b, dds_pw_b, nullptr, nullptr,
      W_dds, 0, 0, nullptr, nullptr, nullptr, 0, acc);
  conv_cc_k<<<g32, b256, 0, stream>>>(Bb, W_proj, proj_b, mask, nullptr, H, 1);

  // ---- hw path ----
  mega_dds_k<<<g32, b256, 0, stream>>>(nullptr, w_in, TTT, nullptr, A, mask,
      pdds_dep_w, pdds_dep_b, pdds_ln_g, pdds_ln_b, pdds_pw_b, post_pre_w, post_pre_b,
      W_pdds, 1, 0, nullptr, nullptr, nullptr, 0, acc);
  conv_cc_k<<<g32, b256, 0, stream>>>(A, W_postproj, post_proj_b, mask, H, GP, 2);

  // ---- init z ----
  init_z_k<<<g256, b256, 0, stream>>>(e_q, mask, paff_m, paff_logs, zbuf, acc);

  // ---- 4 posterior flows (g = GP) ----
  for (int f=0; f<4; f++){
    int s = f & 1;
    mega_dds_k<<<g32, b256, 0, stream>>>(nullptr, zbuf + (size_t)s*TTT, 2*TTT, GP, nullptr, mask,
        p_dep_w + (size_t)f*3*CC*3, p_dep_b + (size_t)f*3*CC,
        p_ln_g + (size_t)f*3*2*CC, p_ln_b + (size_t)f*3*2*CC,
        p_pw_b + (size_t)f*3*CC,
        p_pre_w + (size_t)f*CC, p_pre_b + (size_t)f*CC,
        W_ppw + (size_t)f*3*WSLOT, 1, 1,
        W_pproj + (size_t)f*PSW, p_proj_b + (size_t)f*PP, zbuf, s, acc);
  }

  // ---- transition ----
  final_pre_k<<<g256, b256, 0, stream>>>(zbuf, w_in, mask, aff_m, aff_logs, acc);

  // ---- 4 flows (g = H) ----
  for (int f=0; f<4; f++){
    int s = f & 1;
    mega_dds_k<<<g32, b256, 0, stream>>>(nullptr, zbuf + (size_t)s*TTT, 2*TTT, H, nullptr, mask,
        f_dep_w + (size_t)f*3*CC*3, f_dep_b + (size_t)f*3*CC,
        f_ln_g + (size_t)f*3*2*CC, f_ln_b + (size_t)f*3*2*CC,
        f_pw_b + (size_t)f*3*CC,
        f_pre_w + (size_t)f*CC, f_pre_b + (size_t)f*CC,
        W_fpw + (size_t)f*3*WSLOT, 1, 1,
        W_fproj + (size_t)f*PSW, f_proj_b + (size_t)f*PP, zbuf, s, acc);
  }

  final_post_k<<<g256, b256, 0, stream>>>(zbuf, mask, acc);
  write_out_k<<<1, 64, 0, stream>>>(acc, (float*)d_out, Bn);
}